// Round 1
// baseline (1540.726 us; speedup 1.0000x reference)
//
#include <hip/hip_runtime.h>
#include <math.h>

#define N_NODES 100000
#define N_EDGES 3200000
#define NBLK_EDGE ((N_EDGES + 255) / 256)
#define NBLK_NODE ((N_NODES + 255) / 256)

__device__ __forceinline__ void atomAddF(float* p, float v) {
  unsafeAtomicAdd(p, v);  // global_atomic_add_f32, no CAS loop
}

// ---------------- BatchNorm statistics ----------------
__global__ void bn_reduce(const float4* __restrict__ x, float* __restrict__ bns) {
  float s0 = 0, s1 = 0, s2 = 0, s3 = 0, q0 = 0, q1 = 0, q2 = 0, q3 = 0;
  for (int i = blockIdx.x * blockDim.x + threadIdx.x; i < N_NODES;
       i += gridDim.x * blockDim.x) {
    float4 v = x[i];
    s0 += v.x; s1 += v.y; s2 += v.z; s3 += v.w;
    q0 += v.x * v.x; q1 += v.y * v.y; q2 += v.z * v.z; q3 += v.w * v.w;
  }
#pragma unroll
  for (int o = 32; o; o >>= 1) {
    s0 += __shfl_down(s0, o); s1 += __shfl_down(s1, o);
    s2 += __shfl_down(s2, o); s3 += __shfl_down(s3, o);
    q0 += __shfl_down(q0, o); q1 += __shfl_down(q1, o);
    q2 += __shfl_down(q2, o); q3 += __shfl_down(q3, o);
  }
  __shared__ float red[4][8];
  int w = threadIdx.x >> 6;
  if ((threadIdx.x & 63) == 0) {
    red[w][0] = s0; red[w][1] = s1; red[w][2] = s2; red[w][3] = s3;
    red[w][4] = q0; red[w][5] = q1; red[w][6] = q2; red[w][7] = q3;
  }
  __syncthreads();
  if (threadIdx.x < 8) {
    float acc = red[0][threadIdx.x] + red[1][threadIdx.x] +
                red[2][threadIdx.x] + red[3][threadIdx.x];
    atomicAdd(&bns[threadIdx.x], acc);
  }
}

__global__ void bn_final(const float* __restrict__ bns,
                         const float* __restrict__ gamma,
                         const float* __restrict__ beta,
                         float* __restrict__ ab) {
  int d = threadIdx.x;
  if (d < 4) {
    float mean = bns[d] * (1.0f / N_NODES);
    float var = bns[4 + d] * (1.0f / N_NODES) - mean * mean;
    float a = gamma[d] * rsqrtf(var + 1e-5f);
    ab[d] = a;
    ab[4 + d] = beta[d] - mean * a;  // xn = a*x + b
  }
}

// ---------------- Encoder EdgeConv (+ fused mu/logvar heads) ----------------
__global__ __launch_bounds__(256) void enc_edge(
    const float4* __restrict__ x, const int* __restrict__ esrc,
    const int* __restrict__ etgt, const float* __restrict__ ab,
    const float* __restrict__ eW1, const float* __restrict__ eb1,
    const float* __restrict__ eW2, const float* __restrict__ eb2,
    const float* __restrict__ mW, const float* __restrict__ vW,
    float* __restrict__ msum, float* __restrict__ vsum,
    float* __restrict__ cnt) {
  int e = blockIdx.x * 256 + threadIdx.x;
  if (e >= N_EDGES) return;
  int si = esrc[e], ti = etgt[e];
  float4 xi = x[ti];
  float4 xj = x[si];
  float a0 = ab[0], a1 = ab[1], a2 = ab[2], a3 = ab[3];
  float b0 = ab[4], b1 = ab[5], b2 = ab[6], b3 = ab[7];
  float feat[8];
  feat[0] = fmaf(a0, xi.x, b0);
  feat[1] = fmaf(a1, xi.y, b1);
  feat[2] = fmaf(a2, xi.z, b2);
  feat[3] = fmaf(a3, xi.w, b3);
  feat[4] = a0 * (xj.x - xi.x);  // xn_j - xn_i = a*(xj - xi)
  feat[5] = a1 * (xj.y - xi.y);
  feat[6] = a2 * (xj.z - xi.z);
  feat[7] = a3 * (xj.w - xi.w);
  float h1[32];
#pragma unroll 8
  for (int j = 0; j < 32; ++j) {
    float acc = eb1[j];
#pragma unroll
    for (int k = 0; k < 8; ++k) acc = fmaf(feat[k], eW1[k * 32 + j], acc);
    h1[j] = fmaxf(acc, 0.0f);
  }
  float m0 = 0, m1 = 0, v0 = 0, v1 = 0;
#pragma unroll 4
  for (int j = 0; j < 32; ++j) {
    float acc = eb2[j];
#pragma unroll
    for (int k = 0; k < 32; ++k) acc = fmaf(h1[k], eW2[k * 32 + j], acc);
    float h2 = fmaxf(acc, 0.0f);
    m0 = fmaf(h2, mW[j * 2 + 0], m0);  // fold linear heads inside the mean
    m1 = fmaf(h2, mW[j * 2 + 1], m1);
    v0 = fmaf(h2, vW[j * 2 + 0], v0);
    v1 = fmaf(h2, vW[j * 2 + 1], v1);
  }
  atomAddF(&msum[ti * 2 + 0], m0);
  atomAddF(&msum[ti * 2 + 1], m1);
  atomAddF(&vsum[ti * 2 + 0], v0);
  atomAddF(&vsum[ti * 2 + 1], v1);
  atomAddF(&cnt[ti], 1.0f);
}

// ---------------- mean + bias + reparameterize ----------------
__global__ void node_mid(float* __restrict__ msum, float* __restrict__ vsum,
                         const float* __restrict__ cnt,
                         const float* __restrict__ eps2,
                         const float* __restrict__ mb,
                         const float* __restrict__ vb, float* __restrict__ z) {
  int n = blockIdx.x * 256 + threadIdx.x;
  if (n >= N_NODES) return;
  float inv = 1.0f / fmaxf(cnt[n], 1.0f);
  float mu0 = fmaf(msum[2 * n + 0], inv, mb[0]);
  float mu1 = fmaf(msum[2 * n + 1], inv, mb[1]);
  float lv0 = fmaf(vsum[2 * n + 0], inv, vb[0]);
  float lv1 = fmaf(vsum[2 * n + 1], inv, vb[1]);
  msum[2 * n + 0] = mu0;
  msum[2 * n + 1] = mu1;
  vsum[2 * n + 0] = lv0;
  vsum[2 * n + 1] = lv1;
  z[2 * n + 0] = fmaf(eps2[2 * n + 0], expf(0.5f * lv0), mu0);
  z[2 * n + 1] = fmaf(eps2[2 * n + 1], expf(0.5f * lv1), mu1);
}

// ---------------- Decoder EdgeConv (dW3 applied per edge) ----------------
__global__ __launch_bounds__(256) void dec_edge(
    const float2* __restrict__ z, const int* __restrict__ esrc,
    const int* __restrict__ etgt, const float* __restrict__ dW1,
    const float* __restrict__ db1, const float* __restrict__ dW2,
    const float* __restrict__ db2, const float* __restrict__ dW3,
    const float* __restrict__ db3, float* __restrict__ osum) {
  int e = blockIdx.x * 256 + threadIdx.x;
  if (e >= N_EDGES) return;
  int si = esrc[e], ti = etgt[e];
  float2 zi = z[ti], zj = z[si];
  float f0 = zi.x, f1 = zi.y, f2 = zj.x - zi.x, f3 = zj.y - zi.y;
  float h1[32];
#pragma unroll 8
  for (int j = 0; j < 32; ++j) {
    float acc = db1[j];
    acc = fmaf(f0, dW1[0 * 32 + j], acc);
    acc = fmaf(f1, dW1[1 * 32 + j], acc);
    acc = fmaf(f2, dW1[2 * 32 + j], acc);
    acc = fmaf(f3, dW1[3 * 32 + j], acc);
    h1[j] = fmaxf(acc, 0.0f);
  }
  float o0 = db3[0], o1 = db3[1], o2 = db3[2], o3 = db3[3];
#pragma unroll 4
  for (int j = 0; j < 32; ++j) {
    float acc = db2[j];
#pragma unroll
    for (int k = 0; k < 32; ++k) acc = fmaf(h1[k], dW2[k * 32 + j], acc);
    float h2 = fmaxf(acc, 0.0f);
    o0 = fmaf(h2, dW3[j * 4 + 0], o0);
    o1 = fmaf(h2, dW3[j * 4 + 1], o1);
    o2 = fmaf(h2, dW3[j * 4 + 2], o2);
    o3 = fmaf(h2, dW3[j * 4 + 3], o3);
  }
  atomAddF(&osum[4 * ti + 0], o0);
  atomAddF(&osum[4 * ti + 1], o1);
  atomAddF(&osum[4 * ti + 2], o2);
  atomAddF(&osum[4 * ti + 3], o3);
}

__global__ void node_final(float* __restrict__ osum,
                           const float* __restrict__ cnt) {
  int n = blockIdx.x * 256 + threadIdx.x;
  if (n >= N_NODES) return;
  float inv = 1.0f / fmaxf(cnt[n], 1.0f);
  float4* o4 = (float4*)osum;
  float4 v = o4[n];
  v.x *= inv; v.y *= inv; v.z *= inv; v.w *= inv;
  o4[n] = v;
}

extern "C" void kernel_launch(void* const* d_in, const int* in_sizes, int n_in,
                              void* d_out, int out_size, void* d_ws,
                              size_t ws_size, hipStream_t stream) {
  const float* x = (const float*)d_in[0];
  const int* ei = (const int*)d_in[1];
  const float* eps = (const float*)d_in[2];
  const float* bng = (const float*)d_in[3];
  const float* bnb = (const float*)d_in[4];
  const float* eW1 = (const float*)d_in[5];
  const float* eb1 = (const float*)d_in[6];
  const float* eW2 = (const float*)d_in[7];
  const float* eb2 = (const float*)d_in[8];
  const float* mW = (const float*)d_in[9];
  const float* mb = (const float*)d_in[10];
  const float* vW = (const float*)d_in[11];
  const float* vb = (const float*)d_in[12];
  const float* dW1 = (const float*)d_in[13];
  const float* db1 = (const float*)d_in[14];
  const float* dW2 = (const float*)d_in[15];
  const float* db2 = (const float*)d_in[16];
  const float* dW3 = (const float*)d_in[17];
  const float* db3 = (const float*)d_in[18];

  float* out = (float*)d_out;           // [N,4]: decoder accum -> mean
  float* msum = out + 4 * N_NODES;      // [N,2]: mu accum -> mu
  float* vsum = out + 6 * N_NODES;      // [N,2]: logvar accum -> logvar
  float* wsf = (float*)d_ws;
  float* bns = wsf;                     // 8 floats: sum, sumsq
  float* ab = wsf + 8;                  // 8 floats: scale a[4], shift b[4]
  float* cnt = wsf + 16;                // [N] float counts (shared by both convs)
  float* z = wsf + 16 + N_NODES;        // [N,2]

  hipMemsetAsync(d_out, 0, 8 * N_NODES * sizeof(float), stream);
  hipMemsetAsync(d_ws, 0, (16 + N_NODES) * sizeof(float), stream);

  bn_reduce<<<256, 256, 0, stream>>>((const float4*)x, bns);
  bn_final<<<1, 64, 0, stream>>>(bns, bng, bnb, ab);
  enc_edge<<<NBLK_EDGE, 256, 0, stream>>>((const float4*)x, ei, ei + N_EDGES,
                                          ab, eW1, eb1, eW2, eb2, mW, vW, msum,
                                          vsum, cnt);
  node_mid<<<NBLK_NODE, 256, 0, stream>>>(msum, vsum, cnt, eps, mb, vb, z);
  dec_edge<<<NBLK_EDGE, 256, 0, stream>>>((const float2*)z, ei, ei + N_EDGES,
                                          dW1, db1, dW2, db2, dW3, db3, out);
  node_final<<<NBLK_NODE, 256, 0, stream>>>(out, cnt);
}

// Round 2
// 1536.327 us; speedup vs baseline: 1.0029x; 1.0029x over previous
//
#include <hip/hip_runtime.h>
#include <math.h>

#define N_NODES 100000
#define N_EDGES 3200000
#define NBLK_EDGE ((N_EDGES + 255) / 256)
#define NBLK_NODE ((N_NODES + 255) / 256)

// XCD id of the CU this block runs on (wave-uniform; all waves of a block are
// on one CU). HW-verified on gfx950 (learn_hip m09).
__device__ __forceinline__ int xccId() {
  unsigned x;
  asm volatile("s_getreg_b32 %0, hwreg(HW_REG_XCC_ID)" : "=s"(x));
  return (int)(x & 7);
}

// R>1: scope-less global_atomic_add_f32 -> performed in the LOCAL XCD L2
// (no sc bits, no write-through). Safe because each XCD owns a private copy.
// R==1: device-scope HW fadd (correct across XCDs, but writes through to MALL).
template <int R>
__device__ __forceinline__ void atomAcc(float* p, float v) {
  if (R > 1) {
    asm volatile("global_atomic_add_f32 %0, %1, off" ::"v"(p), "v"(v)
                 : "memory");
  } else {
    unsafeAtomicAdd(p, v);
  }
}

// ---------------- BatchNorm statistics ----------------
__global__ void bn_reduce(const float4* __restrict__ x, float* __restrict__ bns) {
  float s0 = 0, s1 = 0, s2 = 0, s3 = 0, q0 = 0, q1 = 0, q2 = 0, q3 = 0;
  for (int i = blockIdx.x * blockDim.x + threadIdx.x; i < N_NODES;
       i += gridDim.x * blockDim.x) {
    float4 v = x[i];
    s0 += v.x; s1 += v.y; s2 += v.z; s3 += v.w;
    q0 += v.x * v.x; q1 += v.y * v.y; q2 += v.z * v.z; q3 += v.w * v.w;
  }
#pragma unroll
  for (int o = 32; o; o >>= 1) {
    s0 += __shfl_down(s0, o); s1 += __shfl_down(s1, o);
    s2 += __shfl_down(s2, o); s3 += __shfl_down(s3, o);
    q0 += __shfl_down(q0, o); q1 += __shfl_down(q1, o);
    q2 += __shfl_down(q2, o); q3 += __shfl_down(q3, o);
  }
  __shared__ float red[4][8];
  int w = threadIdx.x >> 6;
  if ((threadIdx.x & 63) == 0) {
    red[w][0] = s0; red[w][1] = s1; red[w][2] = s2; red[w][3] = s3;
    red[w][4] = q0; red[w][5] = q1; red[w][6] = q2; red[w][7] = q3;
  }
  __syncthreads();
  if (threadIdx.x < 8) {
    float acc = red[0][threadIdx.x] + red[1][threadIdx.x] +
                red[2][threadIdx.x] + red[3][threadIdx.x];
    atomicAdd(&bns[threadIdx.x], acc);
  }
}

__global__ void bn_final(const float* __restrict__ bns,
                         const float* __restrict__ gamma,
                         const float* __restrict__ beta,
                         float* __restrict__ ab) {
  int d = threadIdx.x;
  if (d < 4) {
    float mean = bns[d] * (1.0f / N_NODES);
    float var = bns[4 + d] * (1.0f / N_NODES) - mean * mean;
    float a = gamma[d] * rsqrtf(var + 1e-5f);
    ab[d] = a;
    ab[4 + d] = beta[d] - mean * a;  // xn = a*x + b
  }
}

// ---------------- Encoder EdgeConv (+ fused mu/logvar heads) ----------------
template <int R>
__global__ __launch_bounds__(256) void enc_edge(
    const float4* __restrict__ x, const int* __restrict__ esrc,
    const int* __restrict__ etgt, const float* __restrict__ ab,
    const float* __restrict__ eW1, const float* __restrict__ eb1,
    const float* __restrict__ eW2, const float* __restrict__ eb2,
    const float* __restrict__ mW, const float* __restrict__ vW,
    float* __restrict__ msumB, float* __restrict__ vsumB,
    float* __restrict__ cntB) {
  int copy = (R > 1) ? xccId() : 0;
  float* msum = msumB + copy * (2 * N_NODES);
  float* vsum = vsumB + copy * (2 * N_NODES);
  float* cnt = cntB + copy * N_NODES;
  int e = blockIdx.x * 256 + threadIdx.x;
  if (e >= N_EDGES) return;
  int si = esrc[e], ti = etgt[e];
  float4 xi = x[ti];
  float4 xj = x[si];
  float a0 = ab[0], a1 = ab[1], a2 = ab[2], a3 = ab[3];
  float b0 = ab[4], b1 = ab[5], b2 = ab[6], b3 = ab[7];
  float feat[8];
  feat[0] = fmaf(a0, xi.x, b0);
  feat[1] = fmaf(a1, xi.y, b1);
  feat[2] = fmaf(a2, xi.z, b2);
  feat[3] = fmaf(a3, xi.w, b3);
  feat[4] = a0 * (xj.x - xi.x);  // xn_j - xn_i = a*(xj - xi)
  feat[5] = a1 * (xj.y - xi.y);
  feat[6] = a2 * (xj.z - xi.z);
  feat[7] = a3 * (xj.w - xi.w);
  float h1[32];
#pragma unroll 8
  for (int j = 0; j < 32; ++j) {
    float acc = eb1[j];
#pragma unroll
    for (int k = 0; k < 8; ++k) acc = fmaf(feat[k], eW1[k * 32 + j], acc);
    h1[j] = fmaxf(acc, 0.0f);
  }
  float m0 = 0, m1 = 0, v0 = 0, v1 = 0;
#pragma unroll 4
  for (int j = 0; j < 32; ++j) {
    float acc = eb2[j];
#pragma unroll
    for (int k = 0; k < 32; ++k) acc = fmaf(h1[k], eW2[k * 32 + j], acc);
    float h2 = fmaxf(acc, 0.0f);
    m0 = fmaf(h2, mW[j * 2 + 0], m0);  // fold linear heads inside the mean
    m1 = fmaf(h2, mW[j * 2 + 1], m1);
    v0 = fmaf(h2, vW[j * 2 + 0], v0);
    v1 = fmaf(h2, vW[j * 2 + 1], v1);
  }
  atomAcc<R>(&msum[ti * 2 + 0], m0);
  atomAcc<R>(&msum[ti * 2 + 1], m1);
  atomAcc<R>(&vsum[ti * 2 + 0], v0);
  atomAcc<R>(&vsum[ti * 2 + 1], v1);
  atomAcc<R>(&cnt[ti], 1.0f);
}

// ---------------- combine copies + mean + bias + reparameterize ----------------
template <int R>
__global__ __launch_bounds__(256) void node_mid(
    const float* __restrict__ msumB, const float* __restrict__ vsumB,
    const float* __restrict__ cntB, const float* __restrict__ eps2,
    const float* __restrict__ mb, const float* __restrict__ vb,
    float* __restrict__ z, float* __restrict__ cntC,
    float* __restrict__ muOut, float* __restrict__ lvOut) {
  int n = blockIdx.x * 256 + threadIdx.x;
  if (n >= N_NODES) return;
  float c = 0, m0 = 0, m1 = 0, v0 = 0, v1 = 0;
#pragma unroll
  for (int r = 0; r < R; ++r) {
    float2 mm = *(const float2*)(msumB + r * (2 * N_NODES) + 2 * n);
    float2 vv = *(const float2*)(vsumB + r * (2 * N_NODES) + 2 * n);
    m0 += mm.x; m1 += mm.y; v0 += vv.x; v1 += vv.y;
    c += cntB[r * N_NODES + n];
  }
  float inv = 1.0f / fmaxf(c, 1.0f);
  float mu0 = fmaf(m0, inv, mb[0]);
  float mu1 = fmaf(m1, inv, mb[1]);
  float lv0 = fmaf(v0, inv, vb[0]);
  float lv1 = fmaf(v1, inv, vb[1]);
  cntC[n] = c;
  muOut[2 * n + 0] = mu0;
  muOut[2 * n + 1] = mu1;
  lvOut[2 * n + 0] = lv0;
  lvOut[2 * n + 1] = lv1;
  z[2 * n + 0] = fmaf(eps2[2 * n + 0], expf(0.5f * lv0), mu0);
  z[2 * n + 1] = fmaf(eps2[2 * n + 1], expf(0.5f * lv1), mu1);
}

// ---------------- Decoder EdgeConv (dW3 applied per edge) ----------------
template <int R>
__global__ __launch_bounds__(256) void dec_edge(
    const float2* __restrict__ z, const int* __restrict__ esrc,
    const int* __restrict__ etgt, const float* __restrict__ dW1,
    const float* __restrict__ db1, const float* __restrict__ dW2,
    const float* __restrict__ db2, const float* __restrict__ dW3,
    const float* __restrict__ db3, float* __restrict__ osumB) {
  int copy = (R > 1) ? xccId() : 0;
  float* osum = osumB + copy * (4 * N_NODES);
  int e = blockIdx.x * 256 + threadIdx.x;
  if (e >= N_EDGES) return;
  int si = esrc[e], ti = etgt[e];
  float2 zi = z[ti], zj = z[si];
  float f0 = zi.x, f1 = zi.y, f2 = zj.x - zi.x, f3 = zj.y - zi.y;
  float h1[32];
#pragma unroll 8
  for (int j = 0; j < 32; ++j) {
    float acc = db1[j];
    acc = fmaf(f0, dW1[0 * 32 + j], acc);
    acc = fmaf(f1, dW1[1 * 32 + j], acc);
    acc = fmaf(f2, dW1[2 * 32 + j], acc);
    acc = fmaf(f3, dW1[3 * 32 + j], acc);
    h1[j] = fmaxf(acc, 0.0f);
  }
  float o0 = db3[0], o1 = db3[1], o2 = db3[2], o3 = db3[3];
#pragma unroll 4
  for (int j = 0; j < 32; ++j) {
    float acc = db2[j];
#pragma unroll
    for (int k = 0; k < 32; ++k) acc = fmaf(h1[k], dW2[k * 32 + j], acc);
    float h2 = fmaxf(acc, 0.0f);
    o0 = fmaf(h2, dW3[j * 4 + 0], o0);
    o1 = fmaf(h2, dW3[j * 4 + 1], o1);
    o2 = fmaf(h2, dW3[j * 4 + 2], o2);
    o3 = fmaf(h2, dW3[j * 4 + 3], o3);
  }
  atomAcc<R>(&osum[4 * ti + 0], o0);
  atomAcc<R>(&osum[4 * ti + 1], o1);
  atomAcc<R>(&osum[4 * ti + 2], o2);
  atomAcc<R>(&osum[4 * ti + 3], o3);
}

template <int R>
__global__ __launch_bounds__(256) void node_final(
    const float* __restrict__ osumB, const float* __restrict__ cntC,
    float* __restrict__ outp) {
  int n = blockIdx.x * 256 + threadIdx.x;
  if (n >= N_NODES) return;
  float o0 = 0, o1 = 0, o2 = 0, o3 = 0;
#pragma unroll
  for (int r = 0; r < R; ++r) {
    float4 v = *(const float4*)(osumB + r * (4 * N_NODES) + 4 * n);
    o0 += v.x; o1 += v.y; o2 += v.z; o3 += v.w;
  }
  float inv = 1.0f / fmaxf(cntC[n], 1.0f);
  float4 res = make_float4(o0 * inv, o1 * inv, o2 * inv, o3 * inv);
  *(float4*)(outp + 4 * n) = res;
}

extern "C" void kernel_launch(void* const* d_in, const int* in_sizes, int n_in,
                              void* d_out, int out_size, void* d_ws,
                              size_t ws_size, hipStream_t stream) {
  const float* x = (const float*)d_in[0];
  const int* ei = (const int*)d_in[1];
  const float* eps = (const float*)d_in[2];
  const float* bng = (const float*)d_in[3];
  const float* bnb = (const float*)d_in[4];
  const float* eW1 = (const float*)d_in[5];
  const float* eb1 = (const float*)d_in[6];
  const float* eW2 = (const float*)d_in[7];
  const float* eb2 = (const float*)d_in[8];
  const float* mW = (const float*)d_in[9];
  const float* mb = (const float*)d_in[10];
  const float* vW = (const float*)d_in[11];
  const float* vb = (const float*)d_in[12];
  const float* dW1 = (const float*)d_in[13];
  const float* db1 = (const float*)d_in[14];
  const float* dW2 = (const float*)d_in[15];
  const float* db2 = (const float*)d_in[16];
  const float* dW3 = (const float*)d_in[17];
  const float* db3 = (const float*)d_in[18];

  float* out = (float*)d_out;       // [N,4] out | [N,2] mu | [N,2] logvar
  float* wsf = (float*)d_ws;
  const size_t N = N_NODES;

  // fast path needs: 16 + 2N (z) + N (cntC) + 8*(2N+2N+N+4N) floats
  const size_t FAST_BYTES = (16 + 3 * N + 8 * 9 * N) * sizeof(float);

  if (ws_size >= FAST_BYTES) {
    // ---- fast path: 8 XCD-local accumulator copies, L2-resident atomics ----
    float* bns = wsf;                      // 8
    float* ab = wsf + 8;                   // 8
    float* z = wsf + 16;                   // 2N
    float* cntC = wsf + 16 + 2 * N;        // N
    float* msumB = wsf + 16 + 3 * N;       // 8 x 2N
    float* vsumB = msumB + 16 * N;         // 8 x 2N
    float* cntB = vsumB + 16 * N;          // 8 x N
    float* osumB = cntB + 8 * N;           // 8 x 4N

    hipMemsetAsync(bns, 0, 8 * sizeof(float), stream);
    hipMemsetAsync(msumB, 0, 72 * N * sizeof(float), stream);

    bn_reduce<<<256, 256, 0, stream>>>((const float4*)x, bns);
    bn_final<<<1, 64, 0, stream>>>(bns, bng, bnb, ab);
    enc_edge<8><<<NBLK_EDGE, 256, 0, stream>>>((const float4*)x, ei,
                                               ei + N_EDGES, ab, eW1, eb1, eW2,
                                               eb2, mW, vW, msumB, vsumB, cntB);
    node_mid<8><<<NBLK_NODE, 256, 0, stream>>>(msumB, vsumB, cntB, eps, mb, vb,
                                               z, cntC, out + 4 * N, out + 6 * N);
    dec_edge<8><<<NBLK_EDGE, 256, 0, stream>>>((const float2*)z, ei,
                                               ei + N_EDGES, dW1, db1, dW2, db2,
                                               dW3, db3, osumB);
    node_final<8><<<NBLK_NODE, 256, 0, stream>>>(osumB, cntC, out);
  } else {
    // ---- fallback: single copy, device-scope atomics (round-1 layout) ----
    float* bns = wsf;                 // 8
    float* ab = wsf + 8;              // 8
    float* cnt = wsf + 16;            // N
    float* z = wsf + 16 + N;          // 2N
    float* msum = out + 4 * N;
    float* vsum = out + 6 * N;

    hipMemsetAsync(d_out, 0, 8 * N * sizeof(float), stream);
    hipMemsetAsync(d_ws, 0, (16 + N) * sizeof(float), stream);

    bn_reduce<<<256, 256, 0, stream>>>((const float4*)x, bns);
    bn_final<<<1, 64, 0, stream>>>(bns, bng, bnb, ab);
    enc_edge<1><<<NBLK_EDGE, 256, 0, stream>>>((const float4*)x, ei,
                                               ei + N_EDGES, ab, eW1, eb1, eW2,
                                               eb2, mW, vW, msum, vsum, cnt);
    node_mid<1><<<NBLK_NODE, 256, 0, stream>>>(msum, vsum, cnt, eps, mb, vb, z,
                                               cnt, msum, vsum);
    dec_edge<1><<<NBLK_EDGE, 256, 0, stream>>>((const float2*)z, ei,
                                               ei + N_EDGES, dW1, db1, dW2, db2,
                                               dW3, db3, out);
    node_final<1><<<NBLK_NODE, 256, 0, stream>>>(out, cnt, out);
  }
}

// Round 3
// 550.335 us; speedup vs baseline: 2.7996x; 2.7916x over previous
//
#include <hip/hip_runtime.h>
#include <math.h>

#define N_NODES 100000
#define N_EDGES 3200000
#define NBLK_EDGE ((N_EDGES + 255) / 256)
#define NBLK_NODE ((N_NODES + 255) / 256)

#define NB 64                                // nodes per bucket
#define NBUCK ((N_NODES + NB - 1) / NB)      // 1563
#define NSLICE 256
#define SLICE (N_EDGES / NSLICE)             // 12500 exact
#define P2 2048                              // pow2 >= NBUCK for the scan

// ---------------- BatchNorm statistics ----------------
__global__ void bn_reduce(const float4* __restrict__ x, float* __restrict__ bns) {
  float s0 = 0, s1 = 0, s2 = 0, s3 = 0, q0 = 0, q1 = 0, q2 = 0, q3 = 0;
  for (int i = blockIdx.x * blockDim.x + threadIdx.x; i < N_NODES;
       i += gridDim.x * blockDim.x) {
    float4 v = x[i];
    s0 += v.x; s1 += v.y; s2 += v.z; s3 += v.w;
    q0 += v.x * v.x; q1 += v.y * v.y; q2 += v.z * v.z; q3 += v.w * v.w;
  }
#pragma unroll
  for (int o = 32; o; o >>= 1) {
    s0 += __shfl_down(s0, o); s1 += __shfl_down(s1, o);
    s2 += __shfl_down(s2, o); s3 += __shfl_down(s3, o);
    q0 += __shfl_down(q0, o); q1 += __shfl_down(q1, o);
    q2 += __shfl_down(q2, o); q3 += __shfl_down(q3, o);
  }
  __shared__ float red[4][8];
  int w = threadIdx.x >> 6;
  if ((threadIdx.x & 63) == 0) {
    red[w][0] = s0; red[w][1] = s1; red[w][2] = s2; red[w][3] = s3;
    red[w][4] = q0; red[w][5] = q1; red[w][6] = q2; red[w][7] = q3;
  }
  __syncthreads();
  if (threadIdx.x < 8) {
    float acc = red[0][threadIdx.x] + red[1][threadIdx.x] +
                red[2][threadIdx.x] + red[3][threadIdx.x];
    atomicAdd(&bns[threadIdx.x], acc);
  }
}

__global__ void bn_final(const float* __restrict__ bns,
                         const float* __restrict__ gamma,
                         const float* __restrict__ beta,
                         float* __restrict__ ab) {
  int d = threadIdx.x;
  if (d < 4) {
    float mean = bns[d] * (1.0f / N_NODES);
    float var = bns[4 + d] * (1.0f / N_NODES) - mean * mean;
    float a = gamma[d] * rsqrtf(var + 1e-5f);
    ab[d] = a;
    ab[4 + d] = beta[d] - mean * a;  // xn = a*x + b
  }
}

// ---------------- counting sort by target bucket (no global atomics) -------
__global__ __launch_bounds__(256) void edge_hist(const int* __restrict__ tgt,
                                                 unsigned* __restrict__ hist) {
  __shared__ unsigned h[NBUCK];
  for (int i = threadIdx.x; i < NBUCK; i += 256) h[i] = 0;
  __syncthreads();
  int e0 = blockIdx.x * SLICE;
  for (int i = threadIdx.x; i < SLICE; i += 256)
    atomicAdd(&h[((unsigned)tgt[e0 + i]) >> 6], 1u);
  __syncthreads();
  for (int i = threadIdx.x; i < NBUCK; i += 256)
    hist[(size_t)blockIdx.x * NBUCK + i] = h[i];
}

__global__ __launch_bounds__(1024) void bucket_scan(unsigned* __restrict__ hist,
                                                    unsigned* __restrict__ start) {
  __shared__ unsigned sa[P2], sb[P2];
  for (int k = threadIdx.x; k < P2; k += 1024) {
    unsigned s = 0;
    if (k < NBUCK) {
#pragma unroll 8
      for (int b = 0; b < NSLICE; ++b) s += hist[(size_t)b * NBUCK + k];
    }
    sa[k] = s;
  }
  __syncthreads();
  unsigned *srcp = sa, *dstp = sb;
  for (int off = 1; off < P2; off <<= 1) {
    for (int k = threadIdx.x; k < P2; k += 1024)
      dstp[k] = srcp[k] + (k >= off ? srcp[k - off] : 0u);
    __syncthreads();
    unsigned* t = srcp; srcp = dstp; dstp = t;
  }
  // srcp = inclusive scan of bucket totals
  for (int k = threadIdx.x; k <= NBUCK; k += 1024)
    start[k] = (k == 0) ? 0u : srcp[k - 1];
  // rewrite hist[b][k] -> exclusive base for (slice b, bucket k)
  for (int k = threadIdx.x; k < NBUCK; k += 1024) {
    unsigned run = (k == 0) ? 0u : srcp[k - 1];
#pragma unroll 4
    for (int b = 0; b < NSLICE; ++b) {
      size_t idx = (size_t)b * NBUCK + k;
      unsigned u = hist[idx];
      hist[idx] = run;
      run += u;
    }
  }
}

__global__ __launch_bounds__(256) void edge_place(
    const int* __restrict__ src, const int* __restrict__ tgt,
    const unsigned* __restrict__ base, unsigned* __restrict__ payload) {
  __shared__ unsigned cur[NBUCK];
  for (int i = threadIdx.x; i < NBUCK; i += 256)
    cur[i] = base[(size_t)blockIdx.x * NBUCK + i];
  __syncthreads();
  int e0 = blockIdx.x * SLICE;
  for (int i = threadIdx.x; i < SLICE; i += 256) {
    unsigned t = (unsigned)tgt[e0 + i];
    unsigned s = (unsigned)src[e0 + i];
    unsigned pos = atomicAdd(&cur[t >> 6], 1u);
    payload[pos] = s | ((t & 63u) << 17);  // src:17b | local-tgt:6b
  }
}

// ---------------- Encoder EdgeConv: one block owns one 64-node bucket ------
__global__ __launch_bounds__(256) void enc_bucket(
    const float4* __restrict__ x, const unsigned* __restrict__ payload,
    const unsigned* __restrict__ start, const float* __restrict__ ab,
    const float* __restrict__ eW1, const float* __restrict__ eb1,
    const float* __restrict__ eW2, const float* __restrict__ eb2,
    const float* __restrict__ mW, const float* __restrict__ vW,
    float2* __restrict__ msum, float2* __restrict__ vsum,
    float* __restrict__ cnt) {
  __shared__ float aM0[NB], aM1[NB], aV0[NB], aV1[NB], aC[NB];
  __shared__ float4 xt[NB];
  int k = blockIdx.x;
  int node0 = k * NB;
  if (threadIdx.x < NB) {
    int n = node0 + threadIdx.x;
    aM0[threadIdx.x] = 0; aM1[threadIdx.x] = 0;
    aV0[threadIdx.x] = 0; aV1[threadIdx.x] = 0; aC[threadIdx.x] = 0;
    xt[threadIdx.x] = x[n < N_NODES ? n : 0];
  }
  __syncthreads();
  float a0 = ab[0], a1 = ab[1], a2 = ab[2], a3 = ab[3];
  float b0 = ab[4], b1 = ab[5], b2 = ab[6], b3 = ab[7];
  unsigned e1 = start[k + 1];
  for (unsigned e = start[k] + threadIdx.x; e < e1; e += 256) {
    unsigned p = payload[e];
    int si = (int)(p & 0x1FFFFu);
    int lti = (int)(p >> 17);
    float4 xj = x[si];
    float4 xi = xt[lti];
    float feat[8];
    feat[0] = fmaf(a0, xi.x, b0);
    feat[1] = fmaf(a1, xi.y, b1);
    feat[2] = fmaf(a2, xi.z, b2);
    feat[3] = fmaf(a3, xi.w, b3);
    feat[4] = a0 * (xj.x - xi.x);  // xn_j - xn_i = a*(xj - xi)
    feat[5] = a1 * (xj.y - xi.y);
    feat[6] = a2 * (xj.z - xi.z);
    feat[7] = a3 * (xj.w - xi.w);
    float h1[32];
#pragma unroll 8
    for (int j = 0; j < 32; ++j) {
      float acc = eb1[j];
#pragma unroll
      for (int kk = 0; kk < 8; ++kk) acc = fmaf(feat[kk], eW1[kk * 32 + j], acc);
      h1[j] = fmaxf(acc, 0.0f);
    }
    float m0 = 0, m1 = 0, v0 = 0, v1 = 0;
#pragma unroll 4
    for (int j = 0; j < 32; ++j) {
      float acc = eb2[j];
#pragma unroll
      for (int kk = 0; kk < 32; ++kk) acc = fmaf(h1[kk], eW2[kk * 32 + j], acc);
      float h2 = fmaxf(acc, 0.0f);
      m0 = fmaf(h2, mW[j * 2 + 0], m0);  // fold mu/logvar heads into the mean
      m1 = fmaf(h2, mW[j * 2 + 1], m1);
      v0 = fmaf(h2, vW[j * 2 + 0], v0);
      v1 = fmaf(h2, vW[j * 2 + 1], v1);
    }
    atomicAdd(&aM0[lti], m0);  // ds_add_f32: LDS-only, no HBM traffic
    atomicAdd(&aM1[lti], m1);
    atomicAdd(&aV0[lti], v0);
    atomicAdd(&aV1[lti], v1);
    atomicAdd(&aC[lti], 1.0f);
  }
  __syncthreads();
  if (threadIdx.x < NB) {
    int n = node0 + threadIdx.x;
    if (n < N_NODES) {  // exclusive bucket ownership: plain stores
      msum[n] = make_float2(aM0[threadIdx.x], aM1[threadIdx.x]);
      vsum[n] = make_float2(aV0[threadIdx.x], aV1[threadIdx.x]);
      cnt[n] = aC[threadIdx.x];
    }
  }
}

// ---------------- mean + bias + reparameterize ----------------
__global__ __launch_bounds__(256) void node_mid(
    float* __restrict__ msum, float* __restrict__ vsum,
    const float* __restrict__ cnt, const float* __restrict__ eps2,
    const float* __restrict__ mb, const float* __restrict__ vb,
    float* __restrict__ z) {
  int n = blockIdx.x * 256 + threadIdx.x;
  if (n >= N_NODES) return;
  float inv = 1.0f / fmaxf(cnt[n], 1.0f);
  float mu0 = fmaf(msum[2 * n + 0], inv, mb[0]);
  float mu1 = fmaf(msum[2 * n + 1], inv, mb[1]);
  float lv0 = fmaf(vsum[2 * n + 0], inv, vb[0]);
  float lv1 = fmaf(vsum[2 * n + 1], inv, vb[1]);
  msum[2 * n + 0] = mu0;
  msum[2 * n + 1] = mu1;
  vsum[2 * n + 0] = lv0;
  vsum[2 * n + 1] = lv1;
  z[2 * n + 0] = fmaf(eps2[2 * n + 0], expf(0.5f * lv0), mu0);
  z[2 * n + 1] = fmaf(eps2[2 * n + 1], expf(0.5f * lv1), mu1);
}

// ---------------- Decoder EdgeConv, bucket-owned ----------------
__global__ __launch_bounds__(256) void dec_bucket(
    const float2* __restrict__ z, const unsigned* __restrict__ payload,
    const unsigned* __restrict__ start, const float* __restrict__ dW1,
    const float* __restrict__ db1, const float* __restrict__ dW2,
    const float* __restrict__ db2, const float* __restrict__ dW3,
    const float* __restrict__ db3, float4* __restrict__ osum) {
  __shared__ float aO0[NB], aO1[NB], aO2[NB], aO3[NB];
  __shared__ float2 zt[NB];
  int k = blockIdx.x;
  int node0 = k * NB;
  if (threadIdx.x < NB) {
    int n = node0 + threadIdx.x;
    aO0[threadIdx.x] = 0; aO1[threadIdx.x] = 0;
    aO2[threadIdx.x] = 0; aO3[threadIdx.x] = 0;
    zt[threadIdx.x] = z[n < N_NODES ? n : 0];
  }
  __syncthreads();
  unsigned e1 = start[k + 1];
  for (unsigned e = start[k] + threadIdx.x; e < e1; e += 256) {
    unsigned p = payload[e];
    int si = (int)(p & 0x1FFFFu);
    int lti = (int)(p >> 17);
    float2 zj = z[si];
    float2 zi = zt[lti];
    float f0 = zi.x, f1 = zi.y, f2 = zj.x - zi.x, f3 = zj.y - zi.y;
    float h1[32];
#pragma unroll 8
    for (int j = 0; j < 32; ++j) {
      float acc = db1[j];
      acc = fmaf(f0, dW1[0 * 32 + j], acc);
      acc = fmaf(f1, dW1[1 * 32 + j], acc);
      acc = fmaf(f2, dW1[2 * 32 + j], acc);
      acc = fmaf(f3, dW1[3 * 32 + j], acc);
      h1[j] = fmaxf(acc, 0.0f);
    }
    float o0 = db3[0], o1 = db3[1], o2 = db3[2], o3 = db3[3];
#pragma unroll 4
    for (int j = 0; j < 32; ++j) {
      float acc = db2[j];
#pragma unroll
      for (int kk = 0; kk < 32; ++kk) acc = fmaf(h1[kk], dW2[kk * 32 + j], acc);
      float h2 = fmaxf(acc, 0.0f);
      o0 = fmaf(h2, dW3[j * 4 + 0], o0);
      o1 = fmaf(h2, dW3[j * 4 + 1], o1);
      o2 = fmaf(h2, dW3[j * 4 + 2], o2);
      o3 = fmaf(h2, dW3[j * 4 + 3], o3);
    }
    atomicAdd(&aO0[lti], o0);
    atomicAdd(&aO1[lti], o1);
    atomicAdd(&aO2[lti], o2);
    atomicAdd(&aO3[lti], o3);
  }
  __syncthreads();
  if (threadIdx.x < NB) {
    int n = node0 + threadIdx.x;
    if (n < N_NODES)
      osum[n] = make_float4(aO0[threadIdx.x], aO1[threadIdx.x],
                            aO2[threadIdx.x], aO3[threadIdx.x]);
  }
}

__global__ __launch_bounds__(256) void node_final(float* __restrict__ osum,
                                                  const float* __restrict__ cnt) {
  int n = blockIdx.x * 256 + threadIdx.x;
  if (n >= N_NODES) return;
  float inv = 1.0f / fmaxf(cnt[n], 1.0f);
  float4* o4 = (float4*)osum;
  float4 v = o4[n];
  v.x *= inv; v.y *= inv; v.z *= inv; v.w *= inv;
  o4[n] = v;
}

// ---------------- fallback (device-scope atomics, round-1 proven) ----------
__device__ __forceinline__ void atomAddF(float* p, float v) {
  unsafeAtomicAdd(p, v);
}

__global__ __launch_bounds__(256) void enc_edge_fb(
    const float4* __restrict__ x, const int* __restrict__ esrc,
    const int* __restrict__ etgt, const float* __restrict__ ab,
    const float* __restrict__ eW1, const float* __restrict__ eb1,
    const float* __restrict__ eW2, const float* __restrict__ eb2,
    const float* __restrict__ mW, const float* __restrict__ vW,
    float* __restrict__ msum, float* __restrict__ vsum,
    float* __restrict__ cnt) {
  int e = blockIdx.x * 256 + threadIdx.x;
  if (e >= N_EDGES) return;
  int si = esrc[e], ti = etgt[e];
  float4 xi = x[ti];
  float4 xj = x[si];
  float a0 = ab[0], a1 = ab[1], a2 = ab[2], a3 = ab[3];
  float b0 = ab[4], b1 = ab[5], b2 = ab[6], b3 = ab[7];
  float feat[8];
  feat[0] = fmaf(a0, xi.x, b0);
  feat[1] = fmaf(a1, xi.y, b1);
  feat[2] = fmaf(a2, xi.z, b2);
  feat[3] = fmaf(a3, xi.w, b3);
  feat[4] = a0 * (xj.x - xi.x);
  feat[5] = a1 * (xj.y - xi.y);
  feat[6] = a2 * (xj.z - xi.z);
  feat[7] = a3 * (xj.w - xi.w);
  float h1[32];
#pragma unroll 8
  for (int j = 0; j < 32; ++j) {
    float acc = eb1[j];
#pragma unroll
    for (int kk = 0; kk < 8; ++kk) acc = fmaf(feat[kk], eW1[kk * 32 + j], acc);
    h1[j] = fmaxf(acc, 0.0f);
  }
  float m0 = 0, m1 = 0, v0 = 0, v1 = 0;
#pragma unroll 4
  for (int j = 0; j < 32; ++j) {
    float acc = eb2[j];
#pragma unroll
    for (int kk = 0; kk < 32; ++kk) acc = fmaf(h1[kk], eW2[kk * 32 + j], acc);
    float h2 = fmaxf(acc, 0.0f);
    m0 = fmaf(h2, mW[j * 2 + 0], m0);
    m1 = fmaf(h2, mW[j * 2 + 1], m1);
    v0 = fmaf(h2, vW[j * 2 + 0], v0);
    v1 = fmaf(h2, vW[j * 2 + 1], v1);
  }
  atomAddF(&msum[ti * 2 + 0], m0);
  atomAddF(&msum[ti * 2 + 1], m1);
  atomAddF(&vsum[ti * 2 + 0], v0);
  atomAddF(&vsum[ti * 2 + 1], v1);
  atomAddF(&cnt[ti], 1.0f);
}

__global__ __launch_bounds__(256) void dec_edge_fb(
    const float2* __restrict__ z, const int* __restrict__ esrc,
    const int* __restrict__ etgt, const float* __restrict__ dW1,
    const float* __restrict__ db1, const float* __restrict__ dW2,
    const float* __restrict__ db2, const float* __restrict__ dW3,
    const float* __restrict__ db3, float* __restrict__ osum) {
  int e = blockIdx.x * 256 + threadIdx.x;
  if (e >= N_EDGES) return;
  int si = esrc[e], ti = etgt[e];
  float2 zi = z[ti], zj = z[si];
  float f0 = zi.x, f1 = zi.y, f2 = zj.x - zi.x, f3 = zj.y - zi.y;
  float h1[32];
#pragma unroll 8
  for (int j = 0; j < 32; ++j) {
    float acc = db1[j];
    acc = fmaf(f0, dW1[0 * 32 + j], acc);
    acc = fmaf(f1, dW1[1 * 32 + j], acc);
    acc = fmaf(f2, dW1[2 * 32 + j], acc);
    acc = fmaf(f3, dW1[3 * 32 + j], acc);
    h1[j] = fmaxf(acc, 0.0f);
  }
  float o0 = db3[0], o1 = db3[1], o2 = db3[2], o3 = db3[3];
#pragma unroll 4
  for (int j = 0; j < 32; ++j) {
    float acc = db2[j];
#pragma unroll
    for (int kk = 0; kk < 32; ++kk) acc = fmaf(h1[kk], dW2[kk * 32 + j], acc);
    float h2 = fmaxf(acc, 0.0f);
    o0 = fmaf(h2, dW3[j * 4 + 0], o0);
    o1 = fmaf(h2, dW3[j * 4 + 1], o1);
    o2 = fmaf(h2, dW3[j * 4 + 2], o2);
    o3 = fmaf(h2, dW3[j * 4 + 3], o3);
  }
  atomAddF(&osum[4 * ti + 0], o0);
  atomAddF(&osum[4 * ti + 1], o1);
  atomAddF(&osum[4 * ti + 2], o2);
  atomAddF(&osum[4 * ti + 3], o3);
}

extern "C" void kernel_launch(void* const* d_in, const int* in_sizes, int n_in,
                              void* d_out, int out_size, void* d_ws,
                              size_t ws_size, hipStream_t stream) {
  const float* x = (const float*)d_in[0];
  const int* ei = (const int*)d_in[1];
  const float* eps = (const float*)d_in[2];
  const float* bng = (const float*)d_in[3];
  const float* bnb = (const float*)d_in[4];
  const float* eW1 = (const float*)d_in[5];
  const float* eb1 = (const float*)d_in[6];
  const float* eW2 = (const float*)d_in[7];
  const float* eb2 = (const float*)d_in[8];
  const float* mW = (const float*)d_in[9];
  const float* mb = (const float*)d_in[10];
  const float* vW = (const float*)d_in[11];
  const float* vb = (const float*)d_in[12];
  const float* dW1 = (const float*)d_in[13];
  const float* db1 = (const float*)d_in[14];
  const float* dW2 = (const float*)d_in[15];
  const float* db2 = (const float*)d_in[16];
  const float* dW3 = (const float*)d_in[17];
  const float* db3 = (const float*)d_in[18];

  float* out = (float*)d_out;  // [N,4] out | [N,2] mu | [N,2] logvar
  const size_t N = N_NODES;
  float* msum = out + 4 * N;
  float* vsum = out + 6 * N;

  // ws layout (sorted path)
  float* wsf = (float*)d_ws;
  float* bns = wsf;                          // 8
  float* ab = wsf + 8;                       // 8
  float* z = wsf + 16;                       // 2N
  float* cnt = wsf + 16 + 2 * N;             // N
  unsigned* start = (unsigned*)(wsf + 16 + 3 * N);      // NBUCK+1
  unsigned* hist = start + (NBUCK + 1);                 // NSLICE*NBUCK
  unsigned* payload = hist + (size_t)NSLICE * NBUCK;    // N_EDGES
  const size_t REQ = (16 + 3 * N) * sizeof(float) +
                     ((size_t)(NBUCK + 1) + (size_t)NSLICE * NBUCK + N_EDGES) *
                         sizeof(unsigned);

  if (ws_size >= REQ) {
    hipMemsetAsync(bns, 0, 8 * sizeof(float), stream);
    bn_reduce<<<256, 256, 0, stream>>>((const float4*)x, bns);
    bn_final<<<1, 64, 0, stream>>>(bns, bng, bnb, ab);
    edge_hist<<<NSLICE, 256, 0, stream>>>(ei + N_EDGES, hist);
    bucket_scan<<<1, 1024, 0, stream>>>(hist, start);
    edge_place<<<NSLICE, 256, 0, stream>>>(ei, ei + N_EDGES, hist, payload);
    enc_bucket<<<NBUCK, 256, 0, stream>>>((const float4*)x, payload, start, ab,
                                          eW1, eb1, eW2, eb2, mW, vW,
                                          (float2*)msum, (float2*)vsum, cnt);
    node_mid<<<NBLK_NODE, 256, 0, stream>>>(msum, vsum, cnt, eps, mb, vb, z);
    dec_bucket<<<NBUCK, 256, 0, stream>>>((const float2*)z, payload, start, dW1,
                                          db1, dW2, db2, dW3, db3, (float4*)out);
    node_final<<<NBLK_NODE, 256, 0, stream>>>(out, cnt);
  } else {
    // fallback: device-scope atomics (round-1 proven path)
    float* cntf = wsf + 16;       // N
    float* zf = wsf + 16 + N;     // 2N
    hipMemsetAsync(d_out, 0, 8 * N * sizeof(float), stream);
    hipMemsetAsync(d_ws, 0, (16 + N) * sizeof(float), stream);
    bn_reduce<<<256, 256, 0, stream>>>((const float4*)x, bns);
    bn_final<<<1, 64, 0, stream>>>(bns, bng, bnb, ab);
    enc_edge_fb<<<NBLK_EDGE, 256, 0, stream>>>((const float4*)x, ei,
                                               ei + N_EDGES, ab, eW1, eb1, eW2,
                                               eb2, mW, vW, msum, vsum, cntf);
    node_mid<<<NBLK_NODE, 256, 0, stream>>>(msum, vsum, cntf, eps, mb, vb, zf);
    dec_edge_fb<<<NBLK_EDGE, 256, 0, stream>>>((const float2*)zf, ei,
                                               ei + N_EDGES, dW1, db1, dW2, db2,
                                               dW3, db3, out);
    node_final<<<NBLK_NODE, 256, 0, stream>>>(out, cntf);
  }
}

// Round 5
// 452.160 us; speedup vs baseline: 3.4075x; 1.2171x over previous
//
#include <hip/hip_runtime.h>
#include <math.h>

#define N_NODES 100000
#define N_EDGES 3200000
#define NBLK_EDGE ((N_EDGES + 255) / 256)
#define NBLK_NODE ((N_NODES + 255) / 256)

#define NB 64                                // nodes per bucket
#define NBUCK ((N_NODES + NB - 1) / NB)      // 1563
#define NSLICE 256
#define SLICE (N_EDGES / NSLICE)             // 12500 exact
#define P2 2048                              // pow2 >= NBUCK for the scan

typedef _Float16 h2f16 __attribute__((ext_vector_type(2)));

// packed-weight table offsets (in half2 units)
#define PK_EW1 0      // 4x32
#define PK_EW2 128    // 16x32
#define PK_HM0 640    // 16
#define PK_HM1 656
#define PK_HV0 672
#define PK_HV1 688
#define PK_DW1 704    // 2x32
#define PK_DW2 768    // 16x32
#define PK_D0 1280    // 16
#define PK_D1 1296
#define PK_D2 1312
#define PK_D3 1328
#define PK_TOTAL 1344

__device__ __forceinline__ h2f16 mkh2(float a, float b) {
  h2f16 h;
  h.x = (_Float16)a;
  h.y = (_Float16)b;
  return h;
}
__device__ __forceinline__ float fdot2(h2f16 a, h2f16 b, float c) {
  return __builtin_amdgcn_fdot2(a, b, c, false);
}
__device__ __forceinline__ h2f16 pk(float a, float b) {
  auto r = __builtin_amdgcn_cvt_pkrtz(a, b);  // v_cvt_pkrtz_f16_f32
  return __builtin_bit_cast(h2f16, r);
}

// ---------------- pack all MLP weights to f16 pairs ----------------
__global__ __launch_bounds__(256) void pack_weights(
    const float* __restrict__ eW1, const float* __restrict__ eW2,
    const float* __restrict__ mW, const float* __restrict__ vW,
    const float* __restrict__ dW1, const float* __restrict__ dW2,
    const float* __restrict__ dW3, h2f16* __restrict__ wpk) {
  int t = threadIdx.x;
  for (int i = t; i < 128; i += 256) {
    int kp = i >> 5, j = i & 31;
    wpk[PK_EW1 + i] = mkh2(eW1[(2 * kp) * 32 + j], eW1[(2 * kp + 1) * 32 + j]);
  }
  for (int i = t; i < 512; i += 256) {
    int kp = i >> 5, j = i & 31;
    wpk[PK_EW2 + i] = mkh2(eW2[(2 * kp) * 32 + j], eW2[(2 * kp + 1) * 32 + j]);
  }
  for (int i = t; i < 16; i += 256) {
    wpk[PK_HM0 + i] = mkh2(mW[4 * i + 0], mW[4 * i + 2]);
    wpk[PK_HM1 + i] = mkh2(mW[4 * i + 1], mW[4 * i + 3]);
    wpk[PK_HV0 + i] = mkh2(vW[4 * i + 0], vW[4 * i + 2]);
    wpk[PK_HV1 + i] = mkh2(vW[4 * i + 1], vW[4 * i + 3]);
  }
  for (int i = t; i < 64; i += 256) {
    int kp = i >> 5, j = i & 31;
    wpk[PK_DW1 + i] = mkh2(dW1[(2 * kp) * 32 + j], dW1[(2 * kp + 1) * 32 + j]);
  }
  for (int i = t; i < 512; i += 256) {
    int kp = i >> 5, j = i & 31;
    wpk[PK_DW2 + i] = mkh2(dW2[(2 * kp) * 32 + j], dW2[(2 * kp + 1) * 32 + j]);
  }
  for (int i = t; i < 16; i += 256) {
    wpk[PK_D0 + i] = mkh2(dW3[8 * i + 0], dW3[8 * i + 4]);
    wpk[PK_D1 + i] = mkh2(dW3[8 * i + 1], dW3[8 * i + 5]);
    wpk[PK_D2 + i] = mkh2(dW3[8 * i + 2], dW3[8 * i + 6]);
    wpk[PK_D3 + i] = mkh2(dW3[8 * i + 3], dW3[8 * i + 7]);
  }
}

// ---------------- BatchNorm statistics ----------------
__global__ void bn_reduce(const float4* __restrict__ x, float* __restrict__ bns) {
  float s0 = 0, s1 = 0, s2 = 0, s3 = 0, q0 = 0, q1 = 0, q2 = 0, q3 = 0;
  for (int i = blockIdx.x * blockDim.x + threadIdx.x; i < N_NODES;
       i += gridDim.x * blockDim.x) {
    float4 v = x[i];
    s0 += v.x; s1 += v.y; s2 += v.z; s3 += v.w;
    q0 += v.x * v.x; q1 += v.y * v.y; q2 += v.z * v.z; q3 += v.w * v.w;
  }
#pragma unroll
  for (int o = 32; o; o >>= 1) {
    s0 += __shfl_down(s0, o); s1 += __shfl_down(s1, o);
    s2 += __shfl_down(s2, o); s3 += __shfl_down(s3, o);
    q0 += __shfl_down(q0, o); q1 += __shfl_down(q1, o);
    q2 += __shfl_down(q2, o); q3 += __shfl_down(q3, o);
  }
  __shared__ float red[4][8];
  int w = threadIdx.x >> 6;
  if ((threadIdx.x & 63) == 0) {
    red[w][0] = s0; red[w][1] = s1; red[w][2] = s2; red[w][3] = s3;
    red[w][4] = q0; red[w][5] = q1; red[w][6] = q2; red[w][7] = q3;
  }
  __syncthreads();
  if (threadIdx.x < 8) {
    float acc = red[0][threadIdx.x] + red[1][threadIdx.x] +
                red[2][threadIdx.x] + red[3][threadIdx.x];
    atomicAdd(&bns[threadIdx.x], acc);
  }
}

__global__ void bn_final(const float* __restrict__ bns,
                         const float* __restrict__ gamma,
                         const float* __restrict__ beta,
                         float* __restrict__ ab) {
  int d = threadIdx.x;
  if (d < 4) {
    float mean = bns[d] * (1.0f / N_NODES);
    float var = bns[4 + d] * (1.0f / N_NODES) - mean * mean;
    float a = gamma[d] * rsqrtf(var + 1e-5f);
    ab[d] = a;
    ab[4 + d] = beta[d] - mean * a;  // xn = a*x + b
  }
}

// ---------------- counting sort by target bucket (no global atomics) -------
__global__ __launch_bounds__(256) void edge_hist(const int* __restrict__ tgt,
                                                 unsigned* __restrict__ hist) {
  __shared__ unsigned h[NBUCK];
  for (int i = threadIdx.x; i < NBUCK; i += 256) h[i] = 0;
  __syncthreads();
  int e0 = blockIdx.x * SLICE;
  for (int i = threadIdx.x; i < SLICE; i += 256)
    atomicAdd(&h[((unsigned)tgt[e0 + i]) >> 6], 1u);
  __syncthreads();
  for (int i = threadIdx.x; i < NBUCK; i += 256)
    hist[(size_t)blockIdx.x * NBUCK + i] = h[i];
}

__global__ __launch_bounds__(1024) void bucket_scan(unsigned* __restrict__ hist,
                                                    unsigned* __restrict__ start) {
  __shared__ unsigned sa[P2], sb[P2];
  for (int k = threadIdx.x; k < P2; k += 1024) {
    unsigned s = 0;
    if (k < NBUCK) {
#pragma unroll 8
      for (int b = 0; b < NSLICE; ++b) s += hist[(size_t)b * NBUCK + k];
    }
    sa[k] = s;
  }
  __syncthreads();
  unsigned *srcp = sa, *dstp = sb;
  for (int off = 1; off < P2; off <<= 1) {
    for (int k = threadIdx.x; k < P2; k += 1024)
      dstp[k] = srcp[k] + (k >= off ? srcp[k - off] : 0u);
    __syncthreads();
    unsigned* t = srcp; srcp = dstp; dstp = t;
  }
  // srcp = inclusive scan of bucket totals
  for (int k = threadIdx.x; k <= NBUCK; k += 1024)
    start[k] = (k == 0) ? 0u : srcp[k - 1];
  // rewrite hist[b][k] -> exclusive base for (slice b, bucket k)
  for (int k = threadIdx.x; k < NBUCK; k += 1024) {
    unsigned run = (k == 0) ? 0u : srcp[k - 1];
#pragma unroll 4
    for (int b = 0; b < NSLICE; ++b) {
      size_t idx = (size_t)b * NBUCK + k;
      unsigned u = hist[idx];
      hist[idx] = run;
      run += u;
    }
  }
}

__global__ __launch_bounds__(256) void edge_place(
    const int* __restrict__ src, const int* __restrict__ tgt,
    const unsigned* __restrict__ base, unsigned* __restrict__ payload) {
  __shared__ unsigned cur[NBUCK];
  for (int i = threadIdx.x; i < NBUCK; i += 256)
    cur[i] = base[(size_t)blockIdx.x * NBUCK + i];
  __syncthreads();
  int e0 = blockIdx.x * SLICE;
  for (int i = threadIdx.x; i < SLICE; i += 256) {
    unsigned t = (unsigned)tgt[e0 + i];
    unsigned s = (unsigned)src[e0 + i];
    unsigned pos = atomicAdd(&cur[t >> 6], 1u);
    payload[pos] = s | ((t & 63u) << 17);  // src:17b | local-tgt:6b
  }
}

// ---------------- Encoder EdgeConv: one block owns one 64-node bucket ------
__global__ __launch_bounds__(256) void enc_bucket(
    const float4* __restrict__ x, const unsigned* __restrict__ payload,
    const unsigned* __restrict__ start, const float* __restrict__ ab,
    const float* __restrict__ eb1, const float* __restrict__ eb2,
    const h2f16* __restrict__ wpk, float2* __restrict__ msum,
    float2* __restrict__ vsum, float* __restrict__ cnt) {
  __shared__ float aM0[NB], aM1[NB], aV0[NB], aV1[NB], aC[NB];
  __shared__ float4 xt[NB];
  int k = blockIdx.x;
  int node0 = k * NB;
  if (threadIdx.x < NB) {
    int n = node0 + threadIdx.x;
    aM0[threadIdx.x] = 0; aM1[threadIdx.x] = 0;
    aV0[threadIdx.x] = 0; aV1[threadIdx.x] = 0; aC[threadIdx.x] = 0;
    xt[threadIdx.x] = x[n < N_NODES ? n : 0];
  }
  __syncthreads();
  float a0 = ab[0], a1 = ab[1], a2 = ab[2], a3 = ab[3];
  float b0 = ab[4], b1 = ab[5], b2 = ab[6], b3 = ab[7];
  unsigned e1 = start[k + 1];
  for (unsigned e = start[k] + threadIdx.x; e < e1; e += 256) {
    unsigned p = payload[e];
    int si = (int)(p & 0x1FFFFu);
    int lti = (int)(p >> 17);
    float4 xj = x[si];
    float4 xi = xt[lti];
    h2f16 fp[4];
    fp[0] = pk(fmaf(a0, xi.x, b0), fmaf(a1, xi.y, b1));
    fp[1] = pk(fmaf(a2, xi.z, b2), fmaf(a3, xi.w, b3));
    fp[2] = pk(a0 * (xj.x - xi.x), a1 * (xj.y - xi.y));
    fp[3] = pk(a2 * (xj.z - xi.z), a3 * (xj.w - xi.w));
    h2f16 h1p[16];
#pragma unroll
    for (int jp = 0; jp < 16; ++jp) {
      float u0 = eb1[2 * jp], u1 = eb1[2 * jp + 1];
#pragma unroll
      for (int kp = 0; kp < 4; ++kp) {
        u0 = fdot2(fp[kp], wpk[PK_EW1 + kp * 32 + 2 * jp], u0);
        u1 = fdot2(fp[kp], wpk[PK_EW1 + kp * 32 + 2 * jp + 1], u1);
      }
      h1p[jp] = pk(fmaxf(u0, 0.0f), fmaxf(u1, 0.0f));
    }
    float m0 = 0, m1 = 0, v0 = 0, v1 = 0;
#pragma unroll 4
    for (int jp = 0; jp < 16; ++jp) {
      float u0 = eb2[2 * jp], u1 = eb2[2 * jp + 1];
#pragma unroll
      for (int kp = 0; kp < 16; ++kp) {
        u0 = fdot2(h1p[kp], wpk[PK_EW2 + kp * 32 + 2 * jp], u0);
        u1 = fdot2(h1p[kp], wpk[PK_EW2 + kp * 32 + 2 * jp + 1], u1);
      }
      h2f16 h2p = pk(fmaxf(u0, 0.0f), fmaxf(u1, 0.0f));
      m0 = fdot2(h2p, wpk[PK_HM0 + jp], m0);  // heads folded into the mean
      m1 = fdot2(h2p, wpk[PK_HM1 + jp], m1);
      v0 = fdot2(h2p, wpk[PK_HV0 + jp], v0);
      v1 = fdot2(h2p, wpk[PK_HV1 + jp], v1);
    }
    atomicAdd(&aM0[lti], m0);  // ds_add_f32: LDS-only, no HBM traffic
    atomicAdd(&aM1[lti], m1);
    atomicAdd(&aV0[lti], v0);
    atomicAdd(&aV1[lti], v1);
    atomicAdd(&aC[lti], 1.0f);
  }
  __syncthreads();
  if (threadIdx.x < NB) {
    int n = node0 + threadIdx.x;
    if (n < N_NODES) {  // exclusive bucket ownership: plain stores
      msum[n] = make_float2(aM0[threadIdx.x], aM1[threadIdx.x]);
      vsum[n] = make_float2(aV0[threadIdx.x], aV1[threadIdx.x]);
      cnt[n] = aC[threadIdx.x];
    }
  }
}

// ---------------- mean + bias + reparameterize ----------------
__global__ __launch_bounds__(256) void node_mid(
    float* __restrict__ msum, float* __restrict__ vsum,
    const float* __restrict__ cnt, const float* __restrict__ eps2,
    const float* __restrict__ mb, const float* __restrict__ vb,
    float* __restrict__ z) {
  int n = blockIdx.x * 256 + threadIdx.x;
  if (n >= N_NODES) return;
  float inv = 1.0f / fmaxf(cnt[n], 1.0f);
  float mu0 = fmaf(msum[2 * n + 0], inv, mb[0]);
  float mu1 = fmaf(msum[2 * n + 1], inv, mb[1]);
  float lv0 = fmaf(vsum[2 * n + 0], inv, vb[0]);
  float lv1 = fmaf(vsum[2 * n + 1], inv, vb[1]);
  msum[2 * n + 0] = mu0;
  msum[2 * n + 1] = mu1;
  vsum[2 * n + 0] = lv0;
  vsum[2 * n + 1] = lv1;
  z[2 * n + 0] = fmaf(eps2[2 * n + 0], expf(0.5f * lv0), mu0);
  z[2 * n + 1] = fmaf(eps2[2 * n + 1], expf(0.5f * lv1), mu1);
}

// ---------------- Decoder EdgeConv, bucket-owned ----------------
__global__ __launch_bounds__(256) void dec_bucket(
    const float2* __restrict__ z, const unsigned* __restrict__ payload,
    const unsigned* __restrict__ start, const float* __restrict__ db1,
    const float* __restrict__ db2, const float* __restrict__ db3,
    const h2f16* __restrict__ wpk, float4* __restrict__ osum) {
  __shared__ float aO0[NB], aO1[NB], aO2[NB], aO3[NB];
  __shared__ float2 zt[NB];
  int k = blockIdx.x;
  int node0 = k * NB;
  if (threadIdx.x < NB) {
    int n = node0 + threadIdx.x;
    aO0[threadIdx.x] = 0; aO1[threadIdx.x] = 0;
    aO2[threadIdx.x] = 0; aO3[threadIdx.x] = 0;
    zt[threadIdx.x] = z[n < N_NODES ? n : 0];
  }
  __syncthreads();
  unsigned e1 = start[k + 1];
  for (unsigned e = start[k] + threadIdx.x; e < e1; e += 256) {
    unsigned p = payload[e];
    int si = (int)(p & 0x1FFFFu);
    int lti = (int)(p >> 17);
    float2 zj = z[si];
    float2 zi = zt[lti];
    h2f16 fp[2];
    fp[0] = pk(zi.x, zi.y);
    fp[1] = pk(zj.x - zi.x, zj.y - zi.y);
    h2f16 h1p[16];
#pragma unroll
    for (int jp = 0; jp < 16; ++jp) {
      float u0 = db1[2 * jp], u1 = db1[2 * jp + 1];
#pragma unroll
      for (int kp = 0; kp < 2; ++kp) {
        u0 = fdot2(fp[kp], wpk[PK_DW1 + kp * 32 + 2 * jp], u0);
        u1 = fdot2(fp[kp], wpk[PK_DW1 + kp * 32 + 2 * jp + 1], u1);
      }
      h1p[jp] = pk(fmaxf(u0, 0.0f), fmaxf(u1, 0.0f));
    }
    float o0 = db3[0], o1 = db3[1], o2 = db3[2], o3 = db3[3];
#pragma unroll 4
    for (int jp = 0; jp < 16; ++jp) {
      float u0 = db2[2 * jp], u1 = db2[2 * jp + 1];
#pragma unroll
      for (int kp = 0; kp < 16; ++kp) {
        u0 = fdot2(h1p[kp], wpk[PK_DW2 + kp * 32 + 2 * jp], u0);
        u1 = fdot2(h1p[kp], wpk[PK_DW2 + kp * 32 + 2 * jp + 1], u1);
      }
      h2f16 h2p = pk(fmaxf(u0, 0.0f), fmaxf(u1, 0.0f));
      o0 = fdot2(h2p, wpk[PK_D0 + jp], o0);  // dW3 folded into the mean
      o1 = fdot2(h2p, wpk[PK_D1 + jp], o1);
      o2 = fdot2(h2p, wpk[PK_D2 + jp], o2);
      o3 = fdot2(h2p, wpk[PK_D3 + jp], o3);
    }
    atomicAdd(&aO0[lti], o0);
    atomicAdd(&aO1[lti], o1);
    atomicAdd(&aO2[lti], o2);
    atomicAdd(&aO3[lti], o3);
  }
  __syncthreads();
  if (threadIdx.x < NB) {
    int n = node0 + threadIdx.x;
    if (n < N_NODES)
      osum[n] = make_float4(aO0[threadIdx.x], aO1[threadIdx.x],
                            aO2[threadIdx.x], aO3[threadIdx.x]);
  }
}

__global__ __launch_bounds__(256) void node_final(float* __restrict__ osum,
                                                  const float* __restrict__ cnt) {
  int n = blockIdx.x * 256 + threadIdx.x;
  if (n >= N_NODES) return;
  float inv = 1.0f / fmaxf(cnt[n], 1.0f);
  float4* o4 = (float4*)osum;
  float4 v = o4[n];
  v.x *= inv; v.y *= inv; v.z *= inv; v.w *= inv;
  o4[n] = v;
}

// ---------------- fallback (device-scope atomics, fp32, round-1 proven) ----
__device__ __forceinline__ void atomAddF(float* p, float v) {
  unsafeAtomicAdd(p, v);
}

__global__ __launch_bounds__(256) void enc_edge_fb(
    const float4* __restrict__ x, const int* __restrict__ esrc,
    const int* __restrict__ etgt, const float* __restrict__ ab,
    const float* __restrict__ eW1, const float* __restrict__ eb1,
    const float* __restrict__ eW2, const float* __restrict__ eb2,
    const float* __restrict__ mW, const float* __restrict__ vW,
    float* __restrict__ msum, float* __restrict__ vsum,
    float* __restrict__ cnt) {
  int e = blockIdx.x * 256 + threadIdx.x;
  if (e >= N_EDGES) return;
  int si = esrc[e], ti = etgt[e];
  float4 xi = x[ti];
  float4 xj = x[si];
  float a0 = ab[0], a1 = ab[1], a2 = ab[2], a3 = ab[3];
  float b0 = ab[4], b1 = ab[5], b2 = ab[6], b3 = ab[7];
  float feat[8];
  feat[0] = fmaf(a0, xi.x, b0);
  feat[1] = fmaf(a1, xi.y, b1);
  feat[2] = fmaf(a2, xi.z, b2);
  feat[3] = fmaf(a3, xi.w, b3);
  feat[4] = a0 * (xj.x - xi.x);
  feat[5] = a1 * (xj.y - xi.y);
  feat[6] = a2 * (xj.z - xi.z);
  feat[7] = a3 * (xj.w - xi.w);
  float h1[32];
#pragma unroll 8
  for (int j = 0; j < 32; ++j) {
    float acc = eb1[j];
#pragma unroll
    for (int kk = 0; kk < 8; ++kk) acc = fmaf(feat[kk], eW1[kk * 32 + j], acc);
    h1[j] = fmaxf(acc, 0.0f);
  }
  float m0 = 0, m1 = 0, v0 = 0, v1 = 0;
#pragma unroll 4
  for (int j = 0; j < 32; ++j) {
    float acc = eb2[j];
#pragma unroll
    for (int kk = 0; kk < 32; ++kk) acc = fmaf(h1[kk], eW2[kk * 32 + j], acc);
    float h2 = fmaxf(acc, 0.0f);
    m0 = fmaf(h2, mW[j * 2 + 0], m0);
    m1 = fmaf(h2, mW[j * 2 + 1], m1);
    v0 = fmaf(h2, vW[j * 2 + 0], v0);
    v1 = fmaf(h2, vW[j * 2 + 1], v1);
  }
  atomAddF(&msum[ti * 2 + 0], m0);
  atomAddF(&msum[ti * 2 + 1], m1);
  atomAddF(&vsum[ti * 2 + 0], v0);
  atomAddF(&vsum[ti * 2 + 1], v1);
  atomAddF(&cnt[ti], 1.0f);
}

__global__ __launch_bounds__(256) void dec_edge_fb(
    const float2* __restrict__ z, const int* __restrict__ esrc,
    const int* __restrict__ etgt, const float* __restrict__ dW1,
    const float* __restrict__ db1, const float* __restrict__ dW2,
    const float* __restrict__ db2, const float* __restrict__ dW3,
    const float* __restrict__ db3, float* __restrict__ osum) {
  int e = blockIdx.x * 256 + threadIdx.x;
  if (e >= N_EDGES) return;
  int si = esrc[e], ti = etgt[e];
  float2 zi = z[ti], zj = z[si];
  float f0 = zi.x, f1 = zi.y, f2 = zj.x - zi.x, f3 = zj.y - zi.y;
  float h1[32];
#pragma unroll 8
  for (int j = 0; j < 32; ++j) {
    float acc = db1[j];
    acc = fmaf(f0, dW1[0 * 32 + j], acc);
    acc = fmaf(f1, dW1[1 * 32 + j], acc);
    acc = fmaf(f2, dW1[2 * 32 + j], acc);
    acc = fmaf(f3, dW1[3 * 32 + j], acc);
    h1[j] = fmaxf(acc, 0.0f);
  }
  float o0 = db3[0], o1 = db3[1], o2 = db3[2], o3 = db3[3];
#pragma unroll 4
  for (int j = 0; j < 32; ++j) {
    float acc = db2[j];
#pragma unroll
    for (int kk = 0; kk < 32; ++kk) acc = fmaf(h1[kk], dW2[kk * 32 + j], acc);
    float h2 = fmaxf(acc, 0.0f);
    o0 = fmaf(h2, dW3[j * 4 + 0], o0);
    o1 = fmaf(h2, dW3[j * 4 + 1], o1);
    o2 = fmaf(h2, dW3[j * 4 + 2], o2);
    o3 = fmaf(h2, dW3[j * 4 + 3], o3);
  }
  atomAddF(&osum[4 * ti + 0], o0);
  atomAddF(&osum[4 * ti + 1], o1);
  atomAddF(&osum[4 * ti + 2], o2);
  atomAddF(&osum[4 * ti + 3], o3);
}

extern "C" void kernel_launch(void* const* d_in, const int* in_sizes, int n_in,
                              void* d_out, int out_size, void* d_ws,
                              size_t ws_size, hipStream_t stream) {
  const float* x = (const float*)d_in[0];
  const int* ei = (const int*)d_in[1];
  const float* eps = (const float*)d_in[2];
  const float* bng = (const float*)d_in[3];
  const float* bnb = (const float*)d_in[4];
  const float* eW1 = (const float*)d_in[5];
  const float* eb1 = (const float*)d_in[6];
  const float* eW2 = (const float*)d_in[7];
  const float* eb2 = (const float*)d_in[8];
  const float* mW = (const float*)d_in[9];
  const float* mb = (const float*)d_in[10];
  const float* vW = (const float*)d_in[11];
  const float* vb = (const float*)d_in[12];
  const float* dW1 = (const float*)d_in[13];
  const float* db1 = (const float*)d_in[14];
  const float* dW2 = (const float*)d_in[15];
  const float* db2 = (const float*)d_in[16];
  const float* dW3 = (const float*)d_in[17];
  const float* db3 = (const float*)d_in[18];

  float* out = (float*)d_out;  // [N,4] out | [N,2] mu | [N,2] logvar
  const size_t N = N_NODES;
  float* msum = out + 4 * N;
  float* vsum = out + 6 * N;

  // ws layout (sorted path)
  float* wsf = (float*)d_ws;
  float* bns = wsf;                          // 8
  float* ab = wsf + 8;                       // 8
  float* z = wsf + 16;                       // 2N
  float* cnt = wsf + 16 + 2 * N;             // N
  unsigned* start = (unsigned*)(wsf + 16 + 3 * N);      // NBUCK+1
  unsigned* hist = start + (NBUCK + 1);                 // NSLICE*NBUCK
  unsigned* payload = hist + (size_t)NSLICE * NBUCK;    // N_EDGES
  h2f16* wpk = (h2f16*)(payload + N_EDGES);             // PK_TOTAL
  const size_t REQ = (16 + 3 * N) * sizeof(float) +
                     ((size_t)(NBUCK + 1) + (size_t)NSLICE * NBUCK + N_EDGES +
                      PK_TOTAL) *
                         sizeof(unsigned);

  if (ws_size >= REQ) {
    (void)hipMemsetAsync(bns, 0, 8 * sizeof(float), stream);
    pack_weights<<<1, 256, 0, stream>>>(eW1, eW2, mW, vW, dW1, dW2, dW3, wpk);
    bn_reduce<<<256, 256, 0, stream>>>((const float4*)x, bns);
    bn_final<<<1, 64, 0, stream>>>(bns, bng, bnb, ab);
    edge_hist<<<NSLICE, 256, 0, stream>>>(ei + N_EDGES, hist);
    bucket_scan<<<1, 1024, 0, stream>>>(hist, start);
    edge_place<<<NSLICE, 256, 0, stream>>>(ei, ei + N_EDGES, hist, payload);
    enc_bucket<<<NBUCK, 256, 0, stream>>>((const float4*)x, payload, start, ab,
                                          eb1, eb2, wpk, (float2*)msum,
                                          (float2*)vsum, cnt);
    node_mid<<<NBLK_NODE, 256, 0, stream>>>(msum, vsum, cnt, eps, mb, vb, z);
    dec_bucket<<<NBUCK, 256, 0, stream>>>((const float2*)z, payload, start, db1,
                                          db2, db3, wpk, (float4*)out);
    node_final<<<NBLK_NODE, 256, 0, stream>>>(out, cnt);
  } else {
    // fallback: device-scope atomics (round-1 proven path)
    float* cntf = wsf + 16;       // N
    float* zf = wsf + 16 + N;     // 2N
    (void)hipMemsetAsync(d_out, 0, 8 * N * sizeof(float), stream);
    (void)hipMemsetAsync(d_ws, 0, (16 + N) * sizeof(float), stream);
    bn_reduce<<<256, 256, 0, stream>>>((const float4*)x, bns);
    bn_final<<<1, 64, 0, stream>>>(bns, bng, bnb, ab);
    enc_edge_fb<<<NBLK_EDGE, 256, 0, stream>>>((const float4*)x, ei,
                                               ei + N_EDGES, ab, eW1, eb1, eW2,
                                               eb2, mW, vW, msum, vsum, cntf);
    node_mid<<<NBLK_NODE, 256, 0, stream>>>(msum, vsum, cntf, eps, mb, vb, zf);
    dec_edge_fb<<<NBLK_EDGE, 256, 0, stream>>>((const float2*)zf, ei,
                                               ei + N_EDGES, dW1, db1, dW2, db2,
                                               dW3, db3, out);
    node_final<<<NBLK_NODE, 256, 0, stream>>>(out, cntf);
  }
}

// Round 6
// 418.091 us; speedup vs baseline: 3.6851x; 1.0815x over previous
//
#include <hip/hip_runtime.h>
#include <math.h>

#define N_NODES 100000
#define N_EDGES 3200000
#define NBLK_EDGE ((N_EDGES + 255) / 256)
#define NBLK_NODE ((N_NODES + 255) / 256)

#define NB 64                                // nodes per bucket
#define NBUCK ((N_NODES + NB - 1) / NB)      // 1563
#define NSLICE 256
#define SLICE (N_EDGES / NSLICE)             // 12500 exact
#define P2 2048                              // pow2 >= NBUCK for the scan

typedef _Float16 h2f16 __attribute__((ext_vector_type(2)));

// packed-weight table offsets (in half2 units)
#define PK_EW1 0      // 4x32
#define PK_EW2 128    // 16x32
#define PK_HM0 640    // 16
#define PK_HM1 656
#define PK_HV0 672
#define PK_HV1 688
#define PK_DW1 704    // 2x32
#define PK_DW2 768    // 16x32
#define PK_D0 1280    // 16
#define PK_D1 1296
#define PK_D2 1312
#define PK_D3 1328
#define PK_TOTAL 1344

__device__ __forceinline__ h2f16 mkh2(float a, float b) {
  h2f16 h;
  h.x = (_Float16)a;
  h.y = (_Float16)b;
  return h;
}
__device__ __forceinline__ float fdot2(h2f16 a, h2f16 b, float c) {
  return __builtin_amdgcn_fdot2(a, b, c, false);
}
__device__ __forceinline__ h2f16 pk(float a, float b) {
  auto r = __builtin_amdgcn_cvt_pkrtz(a, b);  // v_cvt_pkrtz_f16_f32
  return __builtin_bit_cast(h2f16, r);
}

// ---------------- pack all MLP weights to f16 pairs ----------------
__global__ __launch_bounds__(256) void pack_weights(
    const float* __restrict__ eW1, const float* __restrict__ eW2,
    const float* __restrict__ mW, const float* __restrict__ vW,
    const float* __restrict__ dW1, const float* __restrict__ dW2,
    const float* __restrict__ dW3, h2f16* __restrict__ wpk) {
  int t = threadIdx.x;
  for (int i = t; i < 128; i += 256) {
    int kp = i >> 5, j = i & 31;
    wpk[PK_EW1 + i] = mkh2(eW1[(2 * kp) * 32 + j], eW1[(2 * kp + 1) * 32 + j]);
  }
  for (int i = t; i < 512; i += 256) {
    int kp = i >> 5, j = i & 31;
    wpk[PK_EW2 + i] = mkh2(eW2[(2 * kp) * 32 + j], eW2[(2 * kp + 1) * 32 + j]);
  }
  for (int i = t; i < 16; i += 256) {
    wpk[PK_HM0 + i] = mkh2(mW[4 * i + 0], mW[4 * i + 2]);
    wpk[PK_HM1 + i] = mkh2(mW[4 * i + 1], mW[4 * i + 3]);
    wpk[PK_HV0 + i] = mkh2(vW[4 * i + 0], vW[4 * i + 2]);
    wpk[PK_HV1 + i] = mkh2(vW[4 * i + 1], vW[4 * i + 3]);
  }
  for (int i = t; i < 64; i += 256) {
    int kp = i >> 5, j = i & 31;
    wpk[PK_DW1 + i] = mkh2(dW1[(2 * kp) * 32 + j], dW1[(2 * kp + 1) * 32 + j]);
  }
  for (int i = t; i < 512; i += 256) {
    int kp = i >> 5, j = i & 31;
    wpk[PK_DW2 + i] = mkh2(dW2[(2 * kp) * 32 + j], dW2[(2 * kp + 1) * 32 + j]);
  }
  for (int i = t; i < 16; i += 256) {
    wpk[PK_D0 + i] = mkh2(dW3[8 * i + 0], dW3[8 * i + 4]);
    wpk[PK_D1 + i] = mkh2(dW3[8 * i + 1], dW3[8 * i + 5]);
    wpk[PK_D2 + i] = mkh2(dW3[8 * i + 2], dW3[8 * i + 6]);
    wpk[PK_D3 + i] = mkh2(dW3[8 * i + 3], dW3[8 * i + 7]);
  }
}

// ---------------- BatchNorm statistics ----------------
__global__ void bn_reduce(const float4* __restrict__ x, float* __restrict__ bns) {
  float s0 = 0, s1 = 0, s2 = 0, s3 = 0, q0 = 0, q1 = 0, q2 = 0, q3 = 0;
  for (int i = blockIdx.x * blockDim.x + threadIdx.x; i < N_NODES;
       i += gridDim.x * blockDim.x) {
    float4 v = x[i];
    s0 += v.x; s1 += v.y; s2 += v.z; s3 += v.w;
    q0 += v.x * v.x; q1 += v.y * v.y; q2 += v.z * v.z; q3 += v.w * v.w;
  }
#pragma unroll
  for (int o = 32; o; o >>= 1) {
    s0 += __shfl_down(s0, o); s1 += __shfl_down(s1, o);
    s2 += __shfl_down(s2, o); s3 += __shfl_down(s3, o);
    q0 += __shfl_down(q0, o); q1 += __shfl_down(q1, o);
    q2 += __shfl_down(q2, o); q3 += __shfl_down(q3, o);
  }
  __shared__ float red[4][8];
  int w = threadIdx.x >> 6;
  if ((threadIdx.x & 63) == 0) {
    red[w][0] = s0; red[w][1] = s1; red[w][2] = s2; red[w][3] = s3;
    red[w][4] = q0; red[w][5] = q1; red[w][6] = q2; red[w][7] = q3;
  }
  __syncthreads();
  if (threadIdx.x < 8) {
    float acc = red[0][threadIdx.x] + red[1][threadIdx.x] +
                red[2][threadIdx.x] + red[3][threadIdx.x];
    atomicAdd(&bns[threadIdx.x], acc);
  }
}

__global__ void bn_final(const float* __restrict__ bns,
                         const float* __restrict__ gamma,
                         const float* __restrict__ beta,
                         float* __restrict__ ab) {
  int d = threadIdx.x;
  if (d < 4) {
    float mean = bns[d] * (1.0f / N_NODES);
    float var = bns[4 + d] * (1.0f / N_NODES) - mean * mean;
    float a = gamma[d] * rsqrtf(var + 1e-5f);
    ab[d] = a;
    ab[4 + d] = beta[d] - mean * a;  // xn = a*x + b
  }
}

// ---------------- counting sort by target bucket (no global atomics) -------
__global__ __launch_bounds__(256) void edge_hist(const int* __restrict__ tgt,
                                                 unsigned* __restrict__ hist) {
  __shared__ unsigned h[NBUCK];
  for (int i = threadIdx.x; i < NBUCK; i += 256) h[i] = 0;
  __syncthreads();
  int e0 = blockIdx.x * SLICE;
  for (int i = threadIdx.x; i < SLICE; i += 256)
    atomicAdd(&h[((unsigned)tgt[e0 + i]) >> 6], 1u);
  __syncthreads();
  for (int i = threadIdx.x; i < NBUCK; i += 256)
    hist[(size_t)blockIdx.x * NBUCK + i] = h[i];
}

// per-bucket totals (grid-parallel colsum; tot borrows payload scratch)
__global__ __launch_bounds__(256) void bucket_tot(const unsigned* __restrict__ hist,
                                                  unsigned* __restrict__ tot) {
  int k = blockIdx.x * 256 + threadIdx.x;
  if (k >= NBUCK) return;
  unsigned s = 0;
#pragma unroll 8
  for (int b = 0; b < NSLICE; ++b) s += hist[(size_t)b * NBUCK + k];
  tot[k] = s;
}

// exclusive scan of the 1563 bucket totals -> start[]
__global__ __launch_bounds__(1024) void bucket_start(const unsigned* __restrict__ tot,
                                                     unsigned* __restrict__ start) {
  __shared__ unsigned sa[P2], sb[P2];
  for (int k = threadIdx.x; k < P2; k += 1024)
    sa[k] = (k < NBUCK) ? tot[k] : 0u;
  __syncthreads();
  unsigned *srcp = sa, *dstp = sb;
  for (int off = 1; off < P2; off <<= 1) {
    for (int k = threadIdx.x; k < P2; k += 1024)
      dstp[k] = srcp[k] + (k >= off ? srcp[k - off] : 0u);
    __syncthreads();
    unsigned* t = srcp; srcp = dstp; dstp = t;
  }
  for (int k = threadIdx.x; k <= NBUCK; k += 1024)
    start[k] = (k == 0) ? 0u : srcp[k - 1];
}

// hist[s][k] (counts) -> exclusive base per (slice,bucket): one WAVE per bucket
__global__ __launch_bounds__(256) void bucket_bases(unsigned* __restrict__ hist,
                                                    const unsigned* __restrict__ start) {
  int wv = threadIdx.x >> 6, lane = threadIdx.x & 63;
  int k = blockIdx.x * 4 + wv;
  if (k >= NBUCK) return;
  unsigned v0 = hist[(size_t)(4 * lane + 0) * NBUCK + k];
  unsigned v1 = hist[(size_t)(4 * lane + 1) * NBUCK + k];
  unsigned v2 = hist[(size_t)(4 * lane + 2) * NBUCK + k];
  unsigned v3 = hist[(size_t)(4 * lane + 3) * NBUCK + k];
  unsigned p1 = v0, p2 = v0 + v1, p3 = v0 + v1 + v2;
  unsigned s = p3 + v3;
  unsigned incl = s;
#pragma unroll
  for (int off = 1; off < 64; off <<= 1) {
    unsigned t = __shfl_up(incl, off);
    incl += (lane >= off) ? t : 0u;
  }
  unsigned base = start[k] + (incl - s);
  hist[(size_t)(4 * lane + 0) * NBUCK + k] = base;
  hist[(size_t)(4 * lane + 1) * NBUCK + k] = base + p1;
  hist[(size_t)(4 * lane + 2) * NBUCK + k] = base + p2;
  hist[(size_t)(4 * lane + 3) * NBUCK + k] = base + p3;
}

// LDS-staged placement: local counting sort, then bucket-ordered run writes
__global__ __launch_bounds__(256) void edge_place(
    const int* __restrict__ src, const int* __restrict__ tgt,
    const unsigned* __restrict__ hist, const unsigned* __restrict__ start,
    unsigned* __restrict__ payload) {
  __shared__ unsigned stage[SLICE];  // 50000 B
  __shared__ unsigned offA[NBUCK];   // global base - local base
  __shared__ unsigned A2[NBUCK];     // scan space -> local cursors
  int s = blockIdx.x, tid = threadIdx.x;
  for (int k = tid; k < NBUCK; k += 256) {
    unsigned gb = hist[(size_t)s * NBUCK + k];
    unsigned nb = (s == NSLICE - 1) ? start[k + 1]
                                    : hist[(size_t)(s + 1) * NBUCK + k];
    offA[k] = gb;
    A2[k] = nb - gb;  // this slice's count for bucket k
  }
  __syncthreads();
  // in-place inclusive scan of A2 over NBUCK (reg-buffered Hillis-Steele)
  for (int d = 1; d < NBUCK; d <<= 1) {
    unsigned tmp[7];
    int m = 0;
    for (int k = tid; k < NBUCK; k += 256, ++m)
      tmp[m] = (k >= d) ? A2[k - d] : 0u;
    __syncthreads();
    m = 0;
    for (int k = tid; k < NBUCK; k += 256, ++m) A2[k] += tmp[m];
    __syncthreads();
  }
  // exclusive transform + off adjust
  {
    unsigned tmp[7];
    int m = 0;
    for (int k = tid; k < NBUCK; k += 256, ++m)
      tmp[m] = (k == 0) ? 0u : A2[k - 1];
    __syncthreads();
    m = 0;
    for (int k = tid; k < NBUCK; k += 256, ++m) {
      offA[k] -= tmp[m];  // gpos = offA[b] + local_index
      A2[k] = tmp[m];     // local cursor seed = local base
    }
    __syncthreads();
  }
  // place into LDS stage at local sorted positions
  int e0 = s * SLICE;
  for (int i = tid; i < SLICE; i += 256) {
    unsigned t = (unsigned)tgt[e0 + i];
    unsigned sr = (unsigned)src[e0 + i];
    unsigned b = t >> 6;
    unsigned lp = atomicAdd(&A2[b], 1u);
    stage[lp] = sr | ((t & 63u) << 17);  // src:17b | local-tgt:6b
  }
  __syncthreads();
  // write out: bucket-ordered ascending runs (post-cursor A2[b-1] = base of b)
  for (int b = tid; b < NBUCK; b += 256) {
    unsigned beg = (b == 0) ? 0u : A2[b - 1];
    unsigned end = A2[b];
    unsigned go = offA[b];
    for (unsigned i = beg; i < end; ++i) payload[go + i] = stage[i];
  }
}

// ---------------- Encoder EdgeConv: one block owns one 64-node bucket ------
__global__ __launch_bounds__(256) void enc_bucket(
    const float4* __restrict__ x, const unsigned* __restrict__ payload,
    const unsigned* __restrict__ start, const float* __restrict__ ab,
    const float* __restrict__ eb1, const float* __restrict__ eb2,
    const h2f16* __restrict__ wpk, float2* __restrict__ msum,
    float2* __restrict__ vsum, float* __restrict__ cnt) {
  __shared__ float aM0[NB], aM1[NB], aV0[NB], aV1[NB], aC[NB];
  __shared__ float4 xt[NB];
  int k = blockIdx.x;
  int node0 = k * NB;
  if (threadIdx.x < NB) {
    int n = node0 + threadIdx.x;
    aM0[threadIdx.x] = 0; aM1[threadIdx.x] = 0;
    aV0[threadIdx.x] = 0; aV1[threadIdx.x] = 0; aC[threadIdx.x] = 0;
    xt[threadIdx.x] = x[n < N_NODES ? n : 0];
  }
  __syncthreads();
  float a0 = ab[0], a1 = ab[1], a2 = ab[2], a3 = ab[3];
  float b0 = ab[4], b1 = ab[5], b2 = ab[6], b3 = ab[7];
  unsigned e1 = start[k + 1];
  for (unsigned e = start[k] + threadIdx.x; e < e1; e += 256) {
    unsigned p = payload[e];
    int si = (int)(p & 0x1FFFFu);
    int lti = (int)(p >> 17);
    float4 xj = x[si];
    float4 xi = xt[lti];
    h2f16 fp[4];
    fp[0] = pk(fmaf(a0, xi.x, b0), fmaf(a1, xi.y, b1));
    fp[1] = pk(fmaf(a2, xi.z, b2), fmaf(a3, xi.w, b3));
    fp[2] = pk(a0 * (xj.x - xi.x), a1 * (xj.y - xi.y));
    fp[3] = pk(a2 * (xj.z - xi.z), a3 * (xj.w - xi.w));
    h2f16 h1p[16];
#pragma unroll
    for (int jp = 0; jp < 16; ++jp) {
      float u0 = eb1[2 * jp], u1 = eb1[2 * jp + 1];
#pragma unroll
      for (int kp = 0; kp < 4; ++kp) {
        u0 = fdot2(fp[kp], wpk[PK_EW1 + kp * 32 + 2 * jp], u0);
        u1 = fdot2(fp[kp], wpk[PK_EW1 + kp * 32 + 2 * jp + 1], u1);
      }
      h1p[jp] = pk(fmaxf(u0, 0.0f), fmaxf(u1, 0.0f));
    }
    float m0 = 0, m1 = 0, v0 = 0, v1 = 0;
#pragma unroll 4
    for (int jp = 0; jp < 16; ++jp) {
      float u0 = eb2[2 * jp], u1 = eb2[2 * jp + 1];
#pragma unroll
      for (int kp = 0; kp < 16; ++kp) {
        u0 = fdot2(h1p[kp], wpk[PK_EW2 + kp * 32 + 2 * jp], u0);
        u1 = fdot2(h1p[kp], wpk[PK_EW2 + kp * 32 + 2 * jp + 1], u1);
      }
      h2f16 h2p = pk(fmaxf(u0, 0.0f), fmaxf(u1, 0.0f));
      m0 = fdot2(h2p, wpk[PK_HM0 + jp], m0);  // heads folded into the mean
      m1 = fdot2(h2p, wpk[PK_HM1 + jp], m1);
      v0 = fdot2(h2p, wpk[PK_HV0 + jp], v0);
      v1 = fdot2(h2p, wpk[PK_HV1 + jp], v1);
    }
    atomicAdd(&aM0[lti], m0);  // ds_add_f32: LDS-only, no HBM traffic
    atomicAdd(&aM1[lti], m1);
    atomicAdd(&aV0[lti], v0);
    atomicAdd(&aV1[lti], v1);
    atomicAdd(&aC[lti], 1.0f);
  }
  __syncthreads();
  if (threadIdx.x < NB) {
    int n = node0 + threadIdx.x;
    if (n < N_NODES) {  // exclusive bucket ownership: plain stores
      msum[n] = make_float2(aM0[threadIdx.x], aM1[threadIdx.x]);
      vsum[n] = make_float2(aV0[threadIdx.x], aV1[threadIdx.x]);
      cnt[n] = aC[threadIdx.x];
    }
  }
}

// ---------------- mean + bias + reparameterize ----------------
__global__ __launch_bounds__(256) void node_mid(
    float* __restrict__ msum, float* __restrict__ vsum,
    const float* __restrict__ cnt, const float* __restrict__ eps2,
    const float* __restrict__ mb, const float* __restrict__ vb,
    float* __restrict__ z) {
  int n = blockIdx.x * 256 + threadIdx.x;
  if (n >= N_NODES) return;
  float inv = 1.0f / fmaxf(cnt[n], 1.0f);
  float mu0 = fmaf(msum[2 * n + 0], inv, mb[0]);
  float mu1 = fmaf(msum[2 * n + 1], inv, mb[1]);
  float lv0 = fmaf(vsum[2 * n + 0], inv, vb[0]);
  float lv1 = fmaf(vsum[2 * n + 1], inv, vb[1]);
  msum[2 * n + 0] = mu0;
  msum[2 * n + 1] = mu1;
  vsum[2 * n + 0] = lv0;
  vsum[2 * n + 1] = lv1;
  z[2 * n + 0] = fmaf(eps2[2 * n + 0], expf(0.5f * lv0), mu0);
  z[2 * n + 1] = fmaf(eps2[2 * n + 1], expf(0.5f * lv1), mu1);
}

// ---------------- Decoder EdgeConv, bucket-owned ----------------
__global__ __launch_bounds__(256) void dec_bucket(
    const float2* __restrict__ z, const unsigned* __restrict__ payload,
    const unsigned* __restrict__ start, const float* __restrict__ db1,
    const float* __restrict__ db2, const float* __restrict__ db3,
    const h2f16* __restrict__ wpk, float4* __restrict__ osum) {
  __shared__ float aO0[NB], aO1[NB], aO2[NB], aO3[NB];
  __shared__ float2 zt[NB];
  int k = blockIdx.x;
  int node0 = k * NB;
  if (threadIdx.x < NB) {
    int n = node0 + threadIdx.x;
    aO0[threadIdx.x] = 0; aO1[threadIdx.x] = 0;
    aO2[threadIdx.x] = 0; aO3[threadIdx.x] = 0;
    zt[threadIdx.x] = z[n < N_NODES ? n : 0];
  }
  __syncthreads();
  unsigned e1 = start[k + 1];
  for (unsigned e = start[k] + threadIdx.x; e < e1; e += 256) {
    unsigned p = payload[e];
    int si = (int)(p & 0x1FFFFu);
    int lti = (int)(p >> 17);
    float2 zj = z[si];
    float2 zi = zt[lti];
    h2f16 fp[2];
    fp[0] = pk(zi.x, zi.y);
    fp[1] = pk(zj.x - zi.x, zj.y - zi.y);
    h2f16 h1p[16];
#pragma unroll
    for (int jp = 0; jp < 16; ++jp) {
      float u0 = db1[2 * jp], u1 = db1[2 * jp + 1];
#pragma unroll
      for (int kp = 0; kp < 2; ++kp) {
        u0 = fdot2(fp[kp], wpk[PK_DW1 + kp * 32 + 2 * jp], u0);
        u1 = fdot2(fp[kp], wpk[PK_DW1 + kp * 32 + 2 * jp + 1], u1);
      }
      h1p[jp] = pk(fmaxf(u0, 0.0f), fmaxf(u1, 0.0f));
    }
    float o0 = db3[0], o1 = db3[1], o2 = db3[2], o3 = db3[3];
#pragma unroll 4
    for (int jp = 0; jp < 16; ++jp) {
      float u0 = db2[2 * jp], u1 = db2[2 * jp + 1];
#pragma unroll
      for (int kp = 0; kp < 16; ++kp) {
        u0 = fdot2(h1p[kp], wpk[PK_DW2 + kp * 32 + 2 * jp], u0);
        u1 = fdot2(h1p[kp], wpk[PK_DW2 + kp * 32 + 2 * jp + 1], u1);
      }
      h2f16 h2p = pk(fmaxf(u0, 0.0f), fmaxf(u1, 0.0f));
      o0 = fdot2(h2p, wpk[PK_D0 + jp], o0);  // dW3 folded into the mean
      o1 = fdot2(h2p, wpk[PK_D1 + jp], o1);
      o2 = fdot2(h2p, wpk[PK_D2 + jp], o2);
      o3 = fdot2(h2p, wpk[PK_D3 + jp], o3);
    }
    atomicAdd(&aO0[lti], o0);
    atomicAdd(&aO1[lti], o1);
    atomicAdd(&aO2[lti], o2);
    atomicAdd(&aO3[lti], o3);
  }
  __syncthreads();
  if (threadIdx.x < NB) {
    int n = node0 + threadIdx.x;
    if (n < N_NODES)
      osum[n] = make_float4(aO0[threadIdx.x], aO1[threadIdx.x],
                            aO2[threadIdx.x], aO3[threadIdx.x]);
  }
}

__global__ __launch_bounds__(256) void node_final(float* __restrict__ osum,
                                                  const float* __restrict__ cnt) {
  int n = blockIdx.x * 256 + threadIdx.x;
  if (n >= N_NODES) return;
  float inv = 1.0f / fmaxf(cnt[n], 1.0f);
  float4* o4 = (float4*)osum;
  float4 v = o4[n];
  v.x *= inv; v.y *= inv; v.z *= inv; v.w *= inv;
  o4[n] = v;
}

// ---------------- fallback (device-scope atomics, fp32, round-1 proven) ----
__device__ __forceinline__ void atomAddF(float* p, float v) {
  unsafeAtomicAdd(p, v);
}

__global__ __launch_bounds__(256) void enc_edge_fb(
    const float4* __restrict__ x, const int* __restrict__ esrc,
    const int* __restrict__ etgt, const float* __restrict__ ab,
    const float* __restrict__ eW1, const float* __restrict__ eb1,
    const float* __restrict__ eW2, const float* __restrict__ eb2,
    const float* __restrict__ mW, const float* __restrict__ vW,
    float* __restrict__ msum, float* __restrict__ vsum,
    float* __restrict__ cnt) {
  int e = blockIdx.x * 256 + threadIdx.x;
  if (e >= N_EDGES) return;
  int si = esrc[e], ti = etgt[e];
  float4 xi = x[ti];
  float4 xj = x[si];
  float a0 = ab[0], a1 = ab[1], a2 = ab[2], a3 = ab[3];
  float b0 = ab[4], b1 = ab[5], b2 = ab[6], b3 = ab[7];
  float feat[8];
  feat[0] = fmaf(a0, xi.x, b0);
  feat[1] = fmaf(a1, xi.y, b1);
  feat[2] = fmaf(a2, xi.z, b2);
  feat[3] = fmaf(a3, xi.w, b3);
  feat[4] = a0 * (xj.x - xi.x);
  feat[5] = a1 * (xj.y - xi.y);
  feat[6] = a2 * (xj.z - xi.z);
  feat[7] = a3 * (xj.w - xi.w);
  float h1[32];
#pragma unroll 8
  for (int j = 0; j < 32; ++j) {
    float acc = eb1[j];
#pragma unroll
    for (int kk = 0; kk < 8; ++kk) acc = fmaf(feat[kk], eW1[kk * 32 + j], acc);
    h1[j] = fmaxf(acc, 0.0f);
  }
  float m0 = 0, m1 = 0, v0 = 0, v1 = 0;
#pragma unroll 4
  for (int j = 0; j < 32; ++j) {
    float acc = eb2[j];
#pragma unroll
    for (int kk = 0; kk < 32; ++kk) acc = fmaf(h1[kk], eW2[kk * 32 + j], acc);
    float h2 = fmaxf(acc, 0.0f);
    m0 = fmaf(h2, mW[j * 2 + 0], m0);
    m1 = fmaf(h2, mW[j * 2 + 1], m1);
    v0 = fmaf(h2, vW[j * 2 + 0], v0);
    v1 = fmaf(h2, vW[j * 2 + 1], v1);
  }
  atomAddF(&msum[ti * 2 + 0], m0);
  atomAddF(&msum[ti * 2 + 1], m1);
  atomAddF(&vsum[ti * 2 + 0], v0);
  atomAddF(&vsum[ti * 2 + 1], v1);
  atomAddF(&cnt[ti], 1.0f);
}

__global__ __launch_bounds__(256) void dec_edge_fb(
    const float2* __restrict__ z, const int* __restrict__ esrc,
    const int* __restrict__ etgt, const float* __restrict__ dW1,
    const float* __restrict__ db1, const float* __restrict__ dW2,
    const float* __restrict__ db2, const float* __restrict__ dW3,
    const float* __restrict__ db3, float* __restrict__ osum) {
  int e = blockIdx.x * 256 + threadIdx.x;
  if (e >= N_EDGES) return;
  int si = esrc[e], ti = etgt[e];
  float2 zi = z[ti], zj = z[si];
  float f0 = zi.x, f1 = zi.y, f2 = zj.x - zi.x, f3 = zj.y - zi.y;
  float h1[32];
#pragma unroll 8
  for (int j = 0; j < 32; ++j) {
    float acc = db1[j];
    acc = fmaf(f0, dW1[0 * 32 + j], acc);
    acc = fmaf(f1, dW1[1 * 32 + j], acc);
    acc = fmaf(f2, dW1[2 * 32 + j], acc);
    acc = fmaf(f3, dW1[3 * 32 + j], acc);
    h1[j] = fmaxf(acc, 0.0f);
  }
  float o0 = db3[0], o1 = db3[1], o2 = db3[2], o3 = db3[3];
#pragma unroll 4
  for (int j = 0; j < 32; ++j) {
    float acc = db2[j];
#pragma unroll
    for (int kk = 0; kk < 32; ++kk) acc = fmaf(h1[kk], dW2[kk * 32 + j], acc);
    float h2 = fmaxf(acc, 0.0f);
    o0 = fmaf(h2, dW3[j * 4 + 0], o0);
    o1 = fmaf(h2, dW3[j * 4 + 1], o1);
    o2 = fmaf(h2, dW3[j * 4 + 2], o2);
    o3 = fmaf(h2, dW3[j * 4 + 3], o3);
  }
  atomAddF(&osum[4 * ti + 0], o0);
  atomAddF(&osum[4 * ti + 1], o1);
  atomAddF(&osum[4 * ti + 2], o2);
  atomAddF(&osum[4 * ti + 3], o3);
}

extern "C" void kernel_launch(void* const* d_in, const int* in_sizes, int n_in,
                              void* d_out, int out_size, void* d_ws,
                              size_t ws_size, hipStream_t stream) {
  const float* x = (const float*)d_in[0];
  const int* ei = (const int*)d_in[1];
  const float* eps = (const float*)d_in[2];
  const float* bng = (const float*)d_in[3];
  const float* bnb = (const float*)d_in[4];
  const float* eW1 = (const float*)d_in[5];
  const float* eb1 = (const float*)d_in[6];
  const float* eW2 = (const float*)d_in[7];
  const float* eb2 = (const float*)d_in[8];
  const float* mW = (const float*)d_in[9];
  const float* mb = (const float*)d_in[10];
  const float* vW = (const float*)d_in[11];
  const float* vb = (const float*)d_in[12];
  const float* dW1 = (const float*)d_in[13];
  const float* db1 = (const float*)d_in[14];
  const float* dW2 = (const float*)d_in[15];
  const float* db2 = (const float*)d_in[16];
  const float* dW3 = (const float*)d_in[17];
  const float* db3 = (const float*)d_in[18];

  float* out = (float*)d_out;  // [N,4] out | [N,2] mu | [N,2] logvar
  const size_t N = N_NODES;
  float* msum = out + 4 * N;
  float* vsum = out + 6 * N;

  // ws layout (sorted path)
  float* wsf = (float*)d_ws;
  float* bns = wsf;                          // 8
  float* ab = wsf + 8;                       // 8
  float* z = wsf + 16;                       // 2N
  float* cnt = wsf + 16 + 2 * N;             // N
  unsigned* start = (unsigned*)(wsf + 16 + 3 * N);      // NBUCK+1
  unsigned* hist = start + (NBUCK + 1);                 // NSLICE*NBUCK
  unsigned* payload = hist + (size_t)NSLICE * NBUCK;    // N_EDGES
  h2f16* wpk = (h2f16*)(payload + N_EDGES);             // PK_TOTAL
  const size_t REQ = (16 + 3 * N) * sizeof(float) +
                     ((size_t)(NBUCK + 1) + (size_t)NSLICE * NBUCK + N_EDGES +
                      PK_TOTAL) *
                         sizeof(unsigned);

  if (ws_size >= REQ) {
    (void)hipMemsetAsync(bns, 0, 8 * sizeof(float), stream);
    pack_weights<<<1, 256, 0, stream>>>(eW1, eW2, mW, vW, dW1, dW2, dW3, wpk);
    bn_reduce<<<256, 256, 0, stream>>>((const float4*)x, bns);
    bn_final<<<1, 64, 0, stream>>>(bns, bng, bnb, ab);
    edge_hist<<<NSLICE, 256, 0, stream>>>(ei + N_EDGES, hist);
    // tot borrows payload scratch (overwritten later by edge_place)
    bucket_tot<<<(NBUCK + 255) / 256, 256, 0, stream>>>(hist, payload);
    bucket_start<<<1, 1024, 0, stream>>>(payload, start);
    bucket_bases<<<(NBUCK + 3) / 4, 256, 0, stream>>>(hist, start);
    edge_place<<<NSLICE, 256, 0, stream>>>(ei, ei + N_EDGES, hist, start,
                                           payload);
    enc_bucket<<<NBUCK, 256, 0, stream>>>((const float4*)x, payload, start, ab,
                                          eb1, eb2, wpk, (float2*)msum,
                                          (float2*)vsum, cnt);
    node_mid<<<NBLK_NODE, 256, 0, stream>>>(msum, vsum, cnt, eps, mb, vb, z);
    dec_bucket<<<NBUCK, 256, 0, stream>>>((const float2*)z, payload, start, db1,
                                          db2, db3, wpk, (float4*)out);
    node_final<<<NBLK_NODE, 256, 0, stream>>>(out, cnt);
  } else {
    // fallback: device-scope atomics (round-1 proven path)
    float* cntf = wsf + 16;       // N
    float* zf = wsf + 16 + N;     // 2N
    (void)hipMemsetAsync(d_out, 0, 8 * N * sizeof(float), stream);
    (void)hipMemsetAsync(d_ws, 0, (16 + N) * sizeof(float), stream);
    bn_reduce<<<256, 256, 0, stream>>>((const float4*)x, bns);
    bn_final<<<1, 64, 0, stream>>>(bns, bng, bnb, ab);
    enc_edge_fb<<<NBLK_EDGE, 256, 0, stream>>>((const float4*)x, ei,
                                               ei + N_EDGES, ab, eW1, eb1, eW2,
                                               eb2, mW, vW, msum, vsum, cntf);
    node_mid<<<NBLK_NODE, 256, 0, stream>>>(msum, vsum, cntf, eps, mb, vb, zf);
    dec_edge_fb<<<NBLK_EDGE, 256, 0, stream>>>((const float2*)zf, ei,
                                               ei + N_EDGES, dW1, db1, dW2, db2,
                                               dW3, db3, out);
    node_final<<<NBLK_NODE, 256, 0, stream>>>(out, cntf);
  }
}